// Round 5
// baseline (1641.988 us; speedup 1.0000x reference)
//
#include <hip/hip_runtime.h>
#include <hip/hip_fp16.h>

#define DD 8
#define HH 256
#define CH 2048          // edges per chunk (2*NC ~ grid size for phase D)
#define PAYBITS 17       // N <= 131072
#define PAYMASK 0x1FFFF
#define WPITCH 20        // LDS weight row pitch (floats): conflict-free
#define NBLK 1536        // 6 blocks/CU x 256 CUs -- guaranteed by launch_bounds(256,6)

// Barrier state slot layout (ints, 64B-separated where hammered)
#define SL_REG   0       // registration counter
#define SL_XCNT  16      // [16..23] per-XCD block counts (registration)
#define SL_XARR  32      // +16*x   per-XCD monotonic arrive counters
#define SL_XRDY  192     // +16*x   per-XCD ready epochs
#define SL_GAR   352     // global master arrive counter (monotonic)
#define SL_TOTAL 512

// Round-3 lesson (PMC): FETCH 1.88GB is STRUCTURAL (same in r2/r3) -- random
// 32B record gathers evicted from the 4MB/XCD L2 by co-streamed csr/output
// traffic. Baseline ran the same bytes at ~5.8 TB/s; mega ran 2.4 TB/s at
// 12 waves/CU. Fix: (a) 6 blocks/CU (24 waves) for latency hiding;
// (b) __builtin_nontemporal_* on all single-use streams so gather-target
// record arrays stay L2-resident within each phase.
// Round-4 fix: nontemporal builtins need clang ext-vector types, not
// HIP_vector_type (float4) -- route 16B nt accesses through fx4.

typedef float fx4 __attribute__((ext_vector_type(4)));

static __device__ __forceinline__ fx4 ntload4(const float* p) {
    return __builtin_nontemporal_load((const fx4*)p);
}
static __device__ __forceinline__ void ntstore4(float* p, float a, float b,
                                                float c, float d) {
    fx4 v; v[0] = a; v[1] = b; v[2] = c; v[3] = d;
    __builtin_nontemporal_store(v, (fx4*)p);
}

struct Params {
    const float *q, *p, *M, *W1, *b1w, *W2, *b2w, *grav;
    const int *src, *dst;
    float *out;
    float *a, *bn, *qn, *agg1, *gh, *W12p;
    __half2 *hm;
    __half *ya, *bgh, *gz1b;
    float *gq2;                 // alias of qn
    int *csr_in, *csr_out, *start_in, *start_out;
    int *gHistIn, *gHistOut, *cStartIn, *cStartOut, *cCurIn, *cCurOut;
    int *P_in, *P_out;
    int *bar;                   // SL_TOTAL ints, memset to 0
    int N, E, NB, NC;
};

// ------------------- record unpack/accumulate helpers -----------------------
static __device__ __forceinline__
void acc_h8(uint4 r, float acc[8]) {
    float2 f;
    f = __half22float2(*(__half2*)&r.x); acc[0] += f.x; acc[1] += f.y;
    f = __half22float2(*(__half2*)&r.y); acc[2] += f.x; acc[3] += f.y;
    f = __half22float2(*(__half2*)&r.z); acc[4] += f.x; acc[5] += f.y;
    f = __half22float2(*(__half2*)&r.w); acc[6] += f.x; acc[7] += f.y;
}

static __device__ __forceinline__
void unpack_hm(uint4 r0, uint4 r1, float h[8], float m[8]) {
    float2 f;
    f = __half22float2(*(__half2*)&r0.x); h[0] = f.x; m[0] = f.y;
    f = __half22float2(*(__half2*)&r0.y); h[1] = f.x; m[1] = f.y;
    f = __half22float2(*(__half2*)&r0.z); h[2] = f.x; m[2] = f.y;
    f = __half22float2(*(__half2*)&r0.w); h[3] = f.x; m[3] = f.y;
    f = __half22float2(*(__half2*)&r1.x); h[4] = f.x; m[4] = f.y;
    f = __half22float2(*(__half2*)&r1.y); h[5] = f.x; m[5] = f.y;
    f = __half22float2(*(__half2*)&r1.z); h[6] = f.x; m[6] = f.y;
    f = __half22float2(*(__half2*)&r1.w); h[7] = f.x; m[7] = f.y;
}

// gather: csr index loads are NON-TEMPORAL (single-use stream); record loads
// stay cached (the whole point is keeping the 3.2MB record array L2-resident)
static __device__ __forceinline__
void gather_h8(const int* __restrict__ csr, const __half* __restrict__ x,
               int e, int e1, float acc[8]) {
    for (; e + 3 < e1; e += 4) {
        int u0 = __builtin_nontemporal_load(csr + e);
        int u1 = __builtin_nontemporal_load(csr + e + 1);
        int u2 = __builtin_nontemporal_load(csr + e + 2);
        int u3 = __builtin_nontemporal_load(csr + e + 3);
        uint4 r0 = *(const uint4*)(x + (size_t)u0 * DD);
        uint4 r1 = *(const uint4*)(x + (size_t)u1 * DD);
        uint4 r2 = *(const uint4*)(x + (size_t)u2 * DD);
        uint4 r3 = *(const uint4*)(x + (size_t)u3 * DD);
        acc_h8(r0, acc); acc_h8(r1, acc); acc_h8(r2, acc); acc_h8(r3, acc);
    }
    for (; e < e1; e++) {
        int u = __builtin_nontemporal_load(csr + e);
        uint4 r = *(const uint4*)(x + (size_t)u * DD);
        acc_h8(r, acc);
    }
}

// ============================ the mega kernel ===============================

__launch_bounds__(256, 6)
__global__ void mega(Params P) {
    __shared__ __align__(16) float smf[HH * WPITCH + HH];   // 21.5 KB, aliased
    int* smi = (int*)smf;
    const int tid  = threadIdx.x;
    const int gtid = blockIdx.x * 256 + tid;
    const int gstr = gridDim.x * 256;
    int* Bar = P.bar;

    // ---- registration: discover per-XCD block count + populated-XCD count ---
    int xcd = 0, xcnt_ = 1, nx_ = 1, ep = 0;
    if (tid == 0) {
        int xr;
        asm volatile("s_getreg_b32 %0, hwreg(HW_REG_XCC_ID)" : "=s"(xr));
        xcd = xr & 7;
        int pv = __hip_atomic_fetch_add(&Bar[SL_XCNT + xcd], 1,
                                        __ATOMIC_RELAXED, __HIP_MEMORY_SCOPE_AGENT);
        asm volatile("" :: "v"(pv));   // force RMW completion before reg-add
        __hip_atomic_fetch_add(&Bar[SL_REG], 1,
                               __ATOMIC_RELAXED, __HIP_MEMORY_SCOPE_AGENT);
        while (__hip_atomic_load(&Bar[SL_REG], __ATOMIC_RELAXED,
                                 __HIP_MEMORY_SCOPE_AGENT) < NBLK)
            __builtin_amdgcn_s_sleep(2);
        nx_ = 0;
#pragma unroll
        for (int x = 0; x < 8; x++) {
            int c = __hip_atomic_fetch_add(&Bar[SL_XCNT + x], 0,
                                           __ATOMIC_RELAXED, __HIP_MEMORY_SCOPE_AGENT);
            if (x == xcd) xcnt_ = c;
            if (c > 0) nx_++;
        }
    }
    __syncthreads();

    // ---- two-level grid barrier (one L2 wb + one L2 inv per XCD) ----
    auto gsync = [&]() {
        __syncthreads();                 // drains vmcnt: block stores are in L2
        if (tid == 0) {
            ++ep;
            int prev = __hip_atomic_fetch_add(&Bar[SL_XARR + xcd * 16], 1,
                                              __ATOMIC_RELAXED, __HIP_MEMORY_SCOPE_AGENT);
            if (prev == ep * xcnt_ - 1) {
                // XCD master: flush this XCD's L2 (all same-XCD stores)
                __builtin_amdgcn_fence(__ATOMIC_RELEASE, "agent");
                __hip_atomic_fetch_add(&Bar[SL_GAR], 1,
                                       __ATOMIC_RELAXED, __HIP_MEMORY_SCOPE_AGENT);
                while (__hip_atomic_load(&Bar[SL_GAR], __ATOMIC_RELAXED,
                                         __HIP_MEMORY_SCOPE_AGENT) < nx_ * ep)
                    __builtin_amdgcn_s_sleep(1);
                // one L2 (+own L1) invalidate per XCD, before releasing it
                __builtin_amdgcn_fence(__ATOMIC_ACQUIRE, "agent");
                __hip_atomic_store(&Bar[SL_XRDY + xcd * 16], ep,
                                   __ATOMIC_RELAXED, __HIP_MEMORY_SCOPE_AGENT);
            } else {
                while (__hip_atomic_load(&Bar[SL_XRDY + xcd * 16], __ATOMIC_RELAXED,
                                         __HIP_MEMORY_SCOPE_AGENT) < ep)
                    __builtin_amdgcn_s_sleep(1);
                // L2 already fresh (master inv'd); kill only this CU's L1
                asm volatile("buffer_inv" ::: "memory");
            }
        }
        __syncthreads();
    };

    // ---- prologue (no cross-block deps): weight pack + start[N]=E ----
    if (gtid == 0) { P.start_in[P.N] = P.E; P.start_out[P.N] = P.E; }
    for (int t = gtid; t < HH * DD; t += gstr) {
        int j = t >> 3, dd = t & 7;
        P.W12p[j * WPITCH + dd]     = P.W1[dd * HH + j];
        P.W12p[j * WPITCH + 8 + dd] = P.W2[j * DD + dd];
    }
    const float gravv = P.grav[0];

    // ---- phase B: coarse per-chunk histograms (gHist zeroed by memset) ----
    for (int ch = blockIdx.x; ch < P.NC; ch += gridDim.x) {
        int* hIn = smi; int* hOut = smi + 256;
        hIn[tid] = 0; hOut[tid] = 0;
        __syncthreads();
        int lo = ch * CH, hi = min(lo + CH, P.E);
        for (int i = lo + tid; i < hi; i += 256) {
            int dv = __builtin_nontemporal_load(P.dst + i);
            int sv = __builtin_nontemporal_load(P.src + i);
            atomicAdd(&hIn[dv >> 9], 1);
            atomicAdd(&hOut[sv >> 9], 1);
        }
        __syncthreads();
        if (tid < P.NB) {
            int ci = hIn[tid], co = hOut[tid];
            if (ci) atomicAdd(&P.gHistIn[tid], ci);
            if (co) atomicAdd(&P.gHistOut[tid], co);
        }
        __syncthreads();
    }
    gsync();

    // ---- phase C: chunk-level exclusive scan (block 0 only) ----
    if (blockIdx.x == 0) {
#pragma unroll
        for (int dir = 0; dir < 2; dir++) {
            const int* gh_ = dir ? P.gHistOut : P.gHistIn;
            int* cs = dir ? P.cStartOut : P.cStartIn;
            int* cc = dir ? P.cCurOut : P.cCurIn;
            int v = (tid < P.NB) ? gh_[tid] : 0;
            smi[tid] = v;
            __syncthreads();
            for (int off = 1; off < 256; off <<= 1) {
                int t = (tid >= off) ? smi[tid - off] : 0;
                __syncthreads();
                smi[tid] += t;
                __syncthreads();
            }
            if (tid < P.NB) { int ex = smi[tid] - v; cs[tid] = ex; cc[tid] = ex; }
            if (tid == 0) cs[P.NB] = P.E;
            __syncthreads();
        }
    }
    gsync();

    // ---- phase D: partition into per-(chunk, 512-node-bin) runs ----
    for (int vb = blockIdx.x; vb < 2 * P.NC; vb += gridDim.x) {
        int dir = vb >= P.NC;
        int ch  = dir ? vb - P.NC : vb;
        const int* key = dir ? P.src : P.dst;
        const int* pay = dir ? P.dst : P.src;
        int* cCur = dir ? P.cCurOut : P.cCurIn;
        int* Pp   = dir ? P.P_out   : P.P_in;
        int* h = smi;
        h[tid] = 0;
        __syncthreads();
        int lo = ch * CH, hi = min(lo + CH, P.E);
        for (int i = lo + tid; i < hi; i += 256) {
            int kv = __builtin_nontemporal_load(key + i);
            atomicAdd(&h[kv >> 9], 1);
        }
        __syncthreads();
        if (tid < P.NB) {
            int c = h[tid];
            h[tid] = c ? atomicAdd(&cCur[tid], c) : 0;
        }
        __syncthreads();
        for (int i = lo + tid; i < hi; i += 256) {
            int k = __builtin_nontemporal_load(key + i);
            int pl = __builtin_nontemporal_load(pay + i);
            int pos = atomicAdd(&h[k >> 9], 1);
            Pp[pos] = ((k & 511) << PAYBITS) | pl;
        }
        __syncthreads();
    }
    gsync();

    // ---- phase E: fine sort within 512-node bins -> CSR ----
    for (int vb = blockIdx.x; vb < 2 * P.NB; vb += gridDim.x) {
        int dir = vb >= P.NB;
        int b   = dir ? vb - P.NB : vb;
        const int* cStart = dir ? P.cStartOut : P.cStartIn;
        const int* Pp     = dir ? P.P_out     : P.P_in;
        int* start        = dir ? P.start_out : P.start_in;
        int* csr          = dir ? P.csr_out   : P.csr_in;
        int* cnt = smi;              // 512
        int* scn = smi + 512;        // 512
        int* ps  = smi + 1024;       // 256
        int lo = cStart[b], hi = cStart[b + 1];
        cnt[tid] = 0; cnt[tid + 256] = 0;
        __syncthreads();
        for (int i = lo + tid; i < hi; i += 256) {
            int pv = __builtin_nontemporal_load(Pp + i);
            atomicAdd(&cnt[pv >> PAYBITS], 1);
        }
        __syncthreads();
        int c0 = cnt[2 * tid], c1 = cnt[2 * tid + 1];
        int pair = c0 + c1;
        ps[tid] = pair;
        __syncthreads();
        for (int off = 1; off < 256; off <<= 1) {
            int t = (tid >= off) ? ps[tid - off] : 0;
            __syncthreads();
            ps[tid] += t;
            __syncthreads();
        }
        int excl = ps[tid] - pair;
        scn[2 * tid] = excl;
        scn[2 * tid + 1] = excl + c0;
        __syncthreads();
#pragma unroll
        for (int k = 0; k < 2; k++) {
            int i = tid + k * 256;
            int base = lo + scn[i];
            int node = (b << 9) + i;
            if (node < P.N) start[node] = base;
            cnt[i] = base;           // reuse as cursor
        }
        __syncthreads();
        for (int i = lo + tid; i < hi; i += 256) {
            int pv = __builtin_nontemporal_load(Pp + i);
            int pos = atomicAdd(&cnt[pv >> PAYBITS], 1);
            csr[pos] = pv & PAYMASK;
        }
        __syncthreads();
    }
    gsync();

    // ---- phase F: per-node prep (norms, masses, dHdP) ----
    for (int v = gtid; v < P.N; v += gstr) {
        int ei1 = (v + 1 < P.N) ? P.start_in[v + 1]  : P.E;
        int eo1 = (v + 1 < P.N) ? P.start_out[v + 1] : P.E;
        float din  = (float)(ei1 - P.start_in[v]);
        float dout = (float)(eo1 - P.start_out[v]);
        float av = 1.0f / sqrtf(dout > 0.f ? dout : 1.f);
        float bv = 1.0f / sqrtf(din  > 0.f ? din  : 1.f);
        P.a[v] = av; P.bn[v] = bv;
#pragma unroll
        for (int d = 0; d < DD; d++) {
            float m = __builtin_nontemporal_load(P.M + (size_t)v * DD * DD + d * (DD + 1));
            float qv = __builtin_nontemporal_load(P.q + (size_t)v * DD + d);
            float pv = __builtin_nontemporal_load(P.p + (size_t)v * DD + d);
            __half2 hmv;
            hmv.x = __float2half(0.f);
            hmv.y = __float2half(m);
            P.hm[(size_t)v * DD + d] = hmv;
            P.qn[(size_t)v * DD + d] = av * qv;
            P.out[(size_t)v * 2 * DD + DD + d] = pv / m;
        }
    }
    gsync();

    // ---- phase G: agg1 = AggIn(a*q), 2 thr/node ----
    for (int t = gtid; t < 2 * P.N; t += gstr) {
        int v = t >> 1, half = t & 1;
        int e0 = P.start_in[v], e1 = P.start_in[v + 1];
        int mid = e0 + ((e1 - e0) >> 1);
        int e = half ? mid : e0, hiE = half ? e1 : mid;
        float acc[8] = {0.f, 0.f, 0.f, 0.f, 0.f, 0.f, 0.f, 0.f};
        for (; e + 1 < hiE; e += 2) {
            int u0 = __builtin_nontemporal_load(P.csr_in + e);
            int u1 = __builtin_nontemporal_load(P.csr_in + e + 1);
            const float4* p0 = (const float4*)(P.qn + (size_t)u0 * DD);
            const float4* p1 = (const float4*)(P.qn + (size_t)u1 * DD);
            float4 a0 = p0[0], b0 = p0[1], a1 = p1[0], b1 = p1[1];
            acc[0] += a0.x + a1.x; acc[1] += a0.y + a1.y;
            acc[2] += a0.z + a1.z; acc[3] += a0.w + a1.w;
            acc[4] += b0.x + b1.x; acc[5] += b0.y + b1.y;
            acc[6] += b0.z + b1.z; acc[7] += b0.w + b1.w;
        }
        if (e < hiE) {
            int u = __builtin_nontemporal_load(P.csr_in + e);
            const float4* pp = (const float4*)(P.qn + (size_t)u * DD);
            float4 a0 = pp[0], b0 = pp[1];
            acc[0] += a0.x; acc[1] += a0.y; acc[2] += a0.z; acc[3] += a0.w;
            acc[4] += b0.x; acc[5] += b0.y; acc[6] += b0.z; acc[7] += b0.w;
        }
#pragma unroll
        for (int k = 0; k < 8; k++) acc[k] += __shfl_xor(acc[k], 1);
        if (!half) {
            float* yp = P.agg1 + (size_t)v * DD;
            ntstore4(yp,     acc[0], acc[1], acc[2], acc[3]);
            ntstore4(yp + 4, acc[4], acc[5], acc[6], acc[7]);
        }
    }
    gsync();

    // ---- phase H: MLP forward, 16 lanes/node; weights -> LDS once/block ----
    float* sW  = smf;
    float* sb1 = smf + HH * WPITCH;
    for (int i = tid; i < HH * WPITCH; i += 256) sW[i] = P.W12p[i];
    for (int i = tid; i < HH; i += 256) sb1[i] = P.b1w[i];
    __syncthreads();
    for (int t = gtid; t < 16 * P.N; t += gstr) {
        int v = t >> 4, l16 = t & 15, sub = (t >> 3) & 1, d = t & 7;
        float zl = P.bn[v] * __builtin_nontemporal_load(P.agg1 + (size_t)v * DD + d);
        float z[DD];
#pragma unroll
        for (int k = 0; k < DD; k++) z[k] = __shfl(zl, k, 16);
        float acc[DD] = {0.f, 0.f, 0.f, 0.f, 0.f, 0.f, 0.f, 0.f};
        for (int c = 0; c < HH / 16; c += 2) {
            int j0 = (c << 4) | l16, j1 = j0 + 16;
            const float4* w0 = (const float4*)(sW + j0 * WPITCH);
            const float4* w1 = (const float4*)(sW + j1 * WPITCH);
            float4 wa0 = w0[0], wb0 = w0[1], va0 = w0[2], vb0 = w0[3];
            float4 wa1 = w1[0], wb1 = w1[1], va1 = w1[2], vb1 = w1[3];
            float ua0 = fmaf(z[1], wa0.y, fmaf(z[0], wa0.x, sb1[j0]));
            ua0 = fmaf(z[3], wa0.w, fmaf(z[2], wa0.z, ua0));
            float ub0 = fmaf(z[5], wb0.y, z[4] * wb0.x);
            ub0 = fmaf(z[7], wb0.w, fmaf(z[6], wb0.z, ub0));
            float ua1 = fmaf(z[1], wa1.y, fmaf(z[0], wa1.x, sb1[j1]));
            ua1 = fmaf(z[3], wa1.w, fmaf(z[2], wa1.z, ua1));
            float ub1 = fmaf(z[5], wb1.y, z[4] * wb1.x);
            ub1 = fmaf(z[7], wb1.w, fmaf(z[6], wb1.z, ub1));
            float h0 = fmaxf(ua0 + ub0, 0.f);
            float h1 = fmaxf(ua1 + ub1, 0.f);
            acc[0] = fmaf(h0, va0.x, acc[0]); acc[1] = fmaf(h0, va0.y, acc[1]);
            acc[2] = fmaf(h0, va0.z, acc[2]); acc[3] = fmaf(h0, va0.w, acc[3]);
            acc[4] = fmaf(h0, vb0.x, acc[4]); acc[5] = fmaf(h0, vb0.y, acc[5]);
            acc[6] = fmaf(h0, vb0.z, acc[6]); acc[7] = fmaf(h0, vb0.w, acc[7]);
            acc[0] = fmaf(h1, va1.x, acc[0]); acc[1] = fmaf(h1, va1.y, acc[1]);
            acc[2] = fmaf(h1, va1.z, acc[2]); acc[3] = fmaf(h1, va1.w, acc[3]);
            acc[4] = fmaf(h1, vb1.x, acc[4]); acc[5] = fmaf(h1, vb1.y, acc[5]);
            acc[6] = fmaf(h1, vb1.z, acc[6]); acc[7] = fmaf(h1, vb1.w, acc[7]);
        }
#pragma unroll
        for (int m = 1; m < 16; m <<= 1)
#pragma unroll
            for (int k = 0; k < DD; k++) acc[k] += __shfl_xor(acc[k], m);
        float yl = acc[0];
#pragma unroll
        for (int k = 1; k < DD; k++) yl = (d == k) ? acc[k] : yl;
        if (!sub) P.ya[(size_t)v * DD + d] = __float2half(P.a[v] * yl);
    }
    gsync();

    // ---- phase I: h = b*AggIn(ya) + b2 + q -> .x halves of hm ----
    for (int t = gtid; t < 2 * P.N; t += gstr) {
        int v = t >> 1, half = t & 1;
        int e0 = P.start_in[v], e1 = P.start_in[v + 1];
        int mid = e0 + ((e1 - e0) >> 1);
        float acc[8] = {0.f, 0.f, 0.f, 0.f, 0.f, 0.f, 0.f, 0.f};
        gather_h8(P.csr_in, P.ya, half ? mid : e0, half ? e1 : mid, acc);
#pragma unroll
        for (int k = 0; k < 8; k++) acc[k] += __shfl_xor(acc[k], 1);
        if (!half) {
            float bv = P.bn[v];
            const float* qp = P.q + (size_t)v * DD;
            fx4 q0 = ntload4(qp);
            fx4 q1 = ntload4(qp + 4);
            float hq[8] = {q0[0], q0[1], q0[2], q0[3], q1[0], q1[1], q1[2], q1[3]};
            __half2* hp = P.hm + (size_t)v * DD;
#pragma unroll
            for (int k = 0; k < DD; k++) {
                float hval = fmaf(bv, acc[k], P.b2w[k] + hq[k]);
                __half2 cur = hp[k];
                cur.x = __float2half(hval);
                hp[k] = cur;
            }
        }
    }
    gsync();

    // ---- phase J: gravity gradient, 4 thr/node (dir x half-range) ----
    for (int t = gtid; t < 4 * P.N; t += gstr) {
        int v = t >> 2, sub = t & 3, dir = sub >> 1, half = sub & 1;
        const uint4* srec = (const uint4*)(P.hm + (size_t)v * DD);
        uint4 s0 = srec[0], s1 = srec[1];
        float hv[8], mv[8];
        unpack_hm(s0, s1, hv, mv);
        const int* start = dir ? P.start_out : P.start_in;
        const int* csr   = dir ? P.csr_out   : P.csr_in;
        int e0 = start[v], e1 = start[v + 1];
        int mid = e0 + ((e1 - e0) >> 1);
        int e = half ? mid : e0, hiE = half ? e1 : mid;
        float coef = -0.5f * gravv;
        float acc[8] = {0.f, 0.f, 0.f, 0.f, 0.f, 0.f, 0.f, 0.f};
        for (; e + 1 < hiE; e += 2) {
            int u0 = __builtin_nontemporal_load(csr + e);
            int u1 = __builtin_nontemporal_load(csr + e + 1);
            const uint4* r0p = (const uint4*)(P.hm + (size_t)u0 * DD);
            const uint4* r1p = (const uint4*)(P.hm + (size_t)u1 * DD);
            uint4 x0 = r0p[0], x1 = r0p[1], y0 = r1p[0], y1 = r1p[1];
            float hu0[8], mu0[8], hu1[8], mu1[8];
            unpack_hm(x0, x1, hu0, mu0);
            unpack_hm(y0, y1, hu1, mu1);
            float d0[8], d1[8];
            float e20 = 0.f, S0 = 0.f, e21 = 0.f, S1 = 0.f;
#pragma unroll
            for (int k = 0; k < 8; k++) {
                d0[k] = hv[k] - hu0[k];
                d1[k] = hv[k] - hu1[k];
                e20 = fmaf(d0[k], d0[k], e20);
                e21 = fmaf(d1[k], d1[k], e21);
                S0 = fmaf(mv[k], mu0[k], S0);
                S1 = fmaf(mv[k], mu1[k], S1);
            }
            float r0 = rsqrtf(e20), r1 = rsqrtf(e21);
            float c0 = coef * S0 * r0 * r0 * r0;
            float c1 = coef * S1 * r1 * r1 * r1;
#pragma unroll
            for (int k = 0; k < 8; k++)
                acc[k] = fmaf(c0, d0[k], fmaf(c1, d1[k], acc[k]));
        }
        if (e < hiE) {
            int u = __builtin_nontemporal_load(csr + e);
            const uint4* rp = (const uint4*)(P.hm + (size_t)u * DD);
            uint4 x0 = rp[0], x1 = rp[1];
            float hu[8], mu[8];
            unpack_hm(x0, x1, hu, mu);
            float df[8];
            float e2 = 0.f, S = 0.f;
#pragma unroll
            for (int k = 0; k < 8; k++) {
                df[k] = hv[k] - hu[k];
                e2 = fmaf(df[k], df[k], e2);
                S = fmaf(mv[k], mu[k], S);
            }
            float r = rsqrtf(e2);
            float c = coef * S * r * r * r;
#pragma unroll
            for (int k = 0; k < 8; k++) acc[k] = fmaf(c, df[k], acc[k]);
        }
#pragma unroll
        for (int k = 0; k < 8; k++) acc[k] += __shfl_xor(acc[k], 1);
#pragma unroll
        for (int k = 0; k < 8; k++) acc[k] += __shfl_xor(acc[k], 2);
        if (sub == 0) {
            float* gp = P.gh + (size_t)v * DD;
            ntstore4(gp,     acc[0], acc[1], acc[2], acc[3]);
            ntstore4(gp + 4, acc[4], acc[5], acc[6], acc[7]);
            float bv = P.bn[v];
            __half2* bp = (__half2*)(P.bgh + (size_t)v * DD);
            bp[0] = __floats2half2_rn(bv * acc[0], bv * acc[1]);
            bp[1] = __floats2half2_rn(bv * acc[2], bv * acc[3]);
            bp[2] = __floats2half2_rn(bv * acc[4], bv * acc[5]);
            bp[3] = __floats2half2_rn(bv * acc[6], bv * acc[7]);
        }
    }
    gsync();

    // ---- phase K: gq2 = AggOut(bgh), 2 thr/node ----
    for (int t = gtid; t < 2 * P.N; t += gstr) {
        int v = t >> 1, half = t & 1;
        int e0 = P.start_out[v], e1 = P.start_out[v + 1];
        int mid = e0 + ((e1 - e0) >> 1);
        float acc[8] = {0.f, 0.f, 0.f, 0.f, 0.f, 0.f, 0.f, 0.f};
        gather_h8(P.csr_out, P.bgh, half ? mid : e0, half ? e1 : mid, acc);
#pragma unroll
        for (int k = 0; k < 8; k++) acc[k] += __shfl_xor(acc[k], 1);
        if (!half) {
            float* yp = P.gq2 + (size_t)v * DD;
            ntstore4(yp,     acc[0], acc[1], acc[2], acc[3]);
            ntstore4(yp + 4, acc[4], acc[5], acc[6], acc[7]);
        }
    }
    gsync();

    // ---- phase L: MLP backward (weights still live in LDS from phase H) ----
    for (int t = gtid; t < 16 * P.N; t += gstr) {
        int v = t >> 4, l16 = t & 15, sub = (t >> 3) & 1, d = t & 7;
        float bv = P.bn[v], av = P.a[v];
        float zl = bv * __builtin_nontemporal_load(P.agg1 + (size_t)v * DD + d);
        float gl = __builtin_nontemporal_load(P.gq2 + (size_t)v * DD + d);
        float z[DD], gq[DD];
#pragma unroll
        for (int k = 0; k < DD; k++) { z[k] = __shfl(zl, k, 16); gq[k] = __shfl(gl, k, 16); }
        float gz[DD] = {0.f, 0.f, 0.f, 0.f, 0.f, 0.f, 0.f, 0.f};
        for (int c = 0; c < HH / 16; c += 2) {
            int j0 = (c << 4) | l16, j1 = j0 + 16;
            const float4* w0 = (const float4*)(sW + j0 * WPITCH);
            const float4* w1 = (const float4*)(sW + j1 * WPITCH);
            float4 wa0 = w0[0], wb0 = w0[1], va0 = w0[2], vb0 = w0[3];
            float4 wa1 = w1[0], wb1 = w1[1], va1 = w1[2], vb1 = w1[3];
            float ua0 = fmaf(z[1], wa0.y, fmaf(z[0], wa0.x, sb1[j0]));
            ua0 = fmaf(z[3], wa0.w, fmaf(z[2], wa0.z, ua0));
            float ub0 = fmaf(z[5], wb0.y, z[4] * wb0.x);
            ub0 = fmaf(z[7], wb0.w, fmaf(z[6], wb0.z, ub0));
            float ua1 = fmaf(z[1], wa1.y, fmaf(z[0], wa1.x, sb1[j1]));
            ua1 = fmaf(z[3], wa1.w, fmaf(z[2], wa1.z, ua1));
            float ub1 = fmaf(z[5], wb1.y, z[4] * wb1.x);
            ub1 = fmaf(z[7], wb1.w, fmaf(z[6], wb1.z, ub1));
            float u0 = ua0 + ub0, u1 = ua1 + ub1;
            float ga0 = fmaf(gq[1], va0.y, gq[0] * va0.x);
            ga0 = fmaf(gq[3], va0.w, fmaf(gq[2], va0.z, ga0));
            float gb0 = fmaf(gq[5], vb0.y, gq[4] * vb0.x);
            gb0 = fmaf(gq[7], vb0.w, fmaf(gq[6], vb0.z, gb0));
            float ga1 = fmaf(gq[1], va1.y, gq[0] * va1.x);
            ga1 = fmaf(gq[3], va1.w, fmaf(gq[2], va1.z, ga1));
            float gb1 = fmaf(gq[5], vb1.y, gq[4] * vb1.x);
            gb1 = fmaf(gq[7], vb1.w, fmaf(gq[6], vb1.z, gb1));
            float g0 = (u0 > 0.f) ? av * (ga0 + gb0) : 0.f;
            float g1 = (u1 > 0.f) ? av * (ga1 + gb1) : 0.f;
            gz[0] = fmaf(g0, wa0.x, gz[0]); gz[1] = fmaf(g0, wa0.y, gz[1]);
            gz[2] = fmaf(g0, wa0.z, gz[2]); gz[3] = fmaf(g0, wa0.w, gz[3]);
            gz[4] = fmaf(g0, wb0.x, gz[4]); gz[5] = fmaf(g0, wb0.y, gz[5]);
            gz[6] = fmaf(g0, wb0.z, gz[6]); gz[7] = fmaf(g0, wb0.w, gz[7]);
            gz[0] = fmaf(g1, wa1.x, gz[0]); gz[1] = fmaf(g1, wa1.y, gz[1]);
            gz[2] = fmaf(g1, wa1.z, gz[2]); gz[3] = fmaf(g1, wa1.w, gz[3]);
            gz[4] = fmaf(g1, wb1.x, gz[4]); gz[5] = fmaf(g1, wb1.y, gz[5]);
            gz[6] = fmaf(g1, wb1.z, gz[6]); gz[7] = fmaf(g1, wb1.w, gz[7]);
        }
#pragma unroll
        for (int m = 1; m < 16; m <<= 1)
#pragma unroll
            for (int k = 0; k < DD; k++) gz[k] += __shfl_xor(gz[k], m);
        float out_l = gz[0];
#pragma unroll
        for (int k = 1; k < DD; k++) out_l = (d == k) ? gz[k] : out_l;
        if (!sub) P.gz1b[(size_t)v * DD + d] = __float2half(bv * out_l);
    }
    gsync();

    // ---- phase M: out[:, :D] = gh + a * AggOut(gz1b), 2 thr/node ----
    for (int t = gtid; t < 2 * P.N; t += gstr) {
        int v = t >> 1, half = t & 1;
        int e0 = P.start_out[v], e1 = P.start_out[v + 1];
        int mid = e0 + ((e1 - e0) >> 1);
        float acc[8] = {0.f, 0.f, 0.f, 0.f, 0.f, 0.f, 0.f, 0.f};
        gather_h8(P.csr_out, P.gz1b, half ? mid : e0, half ? e1 : mid, acc);
#pragma unroll
        for (int k = 0; k < 8; k++) acc[k] += __shfl_xor(acc[k], 1);
        if (!half) {
            float av = P.a[v];
            const float* gp = P.gh + (size_t)v * DD;
            fx4 g0 = ntload4(gp);
            fx4 g1 = ntload4(gp + 4);
            float4* op = (float4*)(P.out + (size_t)v * 2 * DD);
            op[0] = make_float4(fmaf(av, acc[0], g0[0]), fmaf(av, acc[1], g0[1]),
                                fmaf(av, acc[2], g0[2]), fmaf(av, acc[3], g0[3]));
            op[1] = make_float4(fmaf(av, acc[4], g1[0]), fmaf(av, acc[5], g1[1]),
                                fmaf(av, acc[6], g1[2]), fmaf(av, acc[7], g1[3]));
        }
    }
}

// ============================== launch =====================================

extern "C" void kernel_launch(void* const* d_in, const int* in_sizes, int n_in,
                              void* d_out, int out_size, void* d_ws, size_t ws_size,
                              hipStream_t stream) {
    const float* q    = (const float*)d_in[0];
    const float* p    = (const float*)d_in[1];
    const float* M    = (const float*)d_in[2];
    const int*   src  = (const int*)d_in[3];
    const int*   dst  = (const int*)d_in[4];
    const float* W1   = (const float*)d_in[5];
    const float* b1   = (const float*)d_in[6];
    const float* W2   = (const float*)d_in[7];
    const float* b2   = (const float*)d_in[8];
    const float* grav = (const float*)d_in[9];
    float* out = (float*)d_out;

    int N = in_sizes[0] / DD;
    int E = in_sizes[3];
    size_t n = (size_t)N;
    int NB = (N + 511) >> 9;
    int NC = (E + CH - 1) / CH;

    // ---- data region (46N 4-byte words) ----
    float*   ws   = (float*)d_ws;
    float*   a_   = ws;             // N
    float*   b_   = ws + n;         // N
    float*   qn   = ws + 2  * n;    // 8N f32 (reused as gq2 after phase G)
    float*   agg1 = ws + 10 * n;    // 8N f32 (live through bwd)
    float*   gh   = ws + 18 * n;    // 8N f32
    __half2* hm   = (__half2*)(ws + 26 * n);  // 8N half2 (8N words)
    __half*  ya   = (__half*)(ws + 34 * n);   // 8N half (4N words)
    __half*  bgh  = (__half*)(ws + 38 * n);   // 8N half (4N words)
    __half*  gz1b = (__half*)(ws + 42 * n);   // 8N half (4N words)
    float*   gq2  = qn;

    // ---- int region ----
    int* iw        = (int*)(ws + 46 * n);
    int* csr_in    = iw;                       // E
    int* csr_out   = iw + (size_t)E;           // E
    int* start_in  = iw + 2 * (size_t)E;       // N+1
    int* start_out = start_in + n + 1;         // N+1
    int* gHistIn   = start_out + n + 1;        // 256
    int* gHistOut  = gHistIn + 256;            // 256
    int* cStartIn  = gHistOut + 256;           // NB+1
    int* cStartOut = cStartIn + NB + 1;        // NB+1
    int* cCurIn    = cStartOut + NB + 1;       // NB
    int* cCurOut   = cCurIn + NB;              // NB
    int* iwEnd     = cCurOut + NB;
    float* W12p    = (float*)iwEnd;            // HH*WPITCH = 5120 floats
    int* intAfter  = (int*)(W12p + HH * WPITCH);
    // partition scratch: both dirs alias the data region (dead during build)
    int* P_in  = (E <= 16 * (long long)n) ? (int*)ws            : intAfter;
    int* P_out = (E <= 16 * (long long)n) ? (int*)(ws + 16 * n) : intAfter + E;
    int* barp  = (E <= 16 * (long long)n) ? intAfter            : intAfter + 2 * (size_t)E;

    Params prm;
    prm.q = q; prm.p = p; prm.M = M;
    prm.W1 = W1; prm.b1w = b1; prm.W2 = W2; prm.b2w = b2; prm.grav = grav;
    prm.src = src; prm.dst = dst;
    prm.out = out;
    prm.a = a_; prm.bn = b_; prm.qn = qn; prm.agg1 = agg1; prm.gh = gh;
    prm.W12p = W12p;
    prm.hm = hm; prm.ya = ya; prm.bgh = bgh; prm.gz1b = gz1b; prm.gq2 = gq2;
    prm.csr_in = csr_in; prm.csr_out = csr_out;
    prm.start_in = start_in; prm.start_out = start_out;
    prm.gHistIn = gHistIn; prm.gHistOut = gHistOut;
    prm.cStartIn = cStartIn; prm.cStartOut = cStartOut;
    prm.cCurIn = cCurIn; prm.cCurOut = cCurOut;
    prm.P_in = P_in; prm.P_out = P_out;
    prm.bar = barp;
    prm.N = N; prm.E = E; prm.NB = NB; prm.NC = NC;

    // zero the global hists (512 ints) and the barrier state (SL_TOTAL ints)
    hipMemsetAsync(gHistIn, 0, 512 * sizeof(int), stream);
    hipMemsetAsync(barp, 0, SL_TOTAL * sizeof(int), stream);

    mega<<<dim3(NBLK), dim3(256), 0, stream>>>(prm);
}

// Round 6
// 1618.420 us; speedup vs baseline: 1.0146x; 1.0146x over previous
//
#include <hip/hip_runtime.h>
#include <hip/hip_fp16.h>

#define DD 8
#define HH 256
#define CH 2048          // edges per chunk (2*NC ~ grid size for phase D)
#define PAYBITS 17       // N <= 131072
#define PAYMASK 0x1FFFF
#define WPITCH 20        // LDS weight row pitch (floats): conflict-free
#define NBLK 1536        // 6 blocks/CU x 256 CUs -- guaranteed by launch_bounds(256,6)

// Barrier state slot layout (ints, 64B-separated where hammered)
#define SL_REG   0       // registration counter
#define SL_XCNT  16      // [16..23] per-XCD block counts (registration)
#define SL_XARR  32      // +16*x   per-XCD monotonic arrive counters
#define SL_XRDY  192     // +16*x   per-XCD ready epochs
#define SL_GAR   352     // global master arrive counter (monotonic)
#define SL_TOTAL 512

// Round-5 lesson (PMC): nt hints were PURE HARM (+1.18GB traffic = +525us at
// the pinned ~2.25 TB/s); occupancy lever worked (36->73%) but was confounded
// by nt's latency/concurrency penalty. This round: EXACT round-3 kernel
// (1103us, no nt) with ONLY the occupancy change -- the clean experiment.
// If latency-bound: ~600-700us. If still ~1100us: beyond-L2 throughput is
// structurally pinned by in-kernel L2 invalidation -> revert to multi-kernel.

struct Params {
    const float *q, *p, *M, *W1, *b1w, *W2, *b2w, *grav;
    const int *src, *dst;
    float *out;
    float *a, *bn, *qn, *agg1, *gh, *W12p;
    __half2 *hm;
    __half *ya, *bgh, *gz1b;
    float *gq2;                 // alias of qn
    int *csr_in, *csr_out, *start_in, *start_out;
    int *gHistIn, *gHistOut, *cStartIn, *cStartOut, *cCurIn, *cCurOut;
    int *P_in, *P_out;
    int *bar;                   // SL_TOTAL ints, memset to 0
    int N, E, NB, NC;
};

// ------------------- record unpack/accumulate helpers -----------------------
static __device__ __forceinline__
void acc_h8(uint4 r, float acc[8]) {
    float2 f;
    f = __half22float2(*(__half2*)&r.x); acc[0] += f.x; acc[1] += f.y;
    f = __half22float2(*(__half2*)&r.y); acc[2] += f.x; acc[3] += f.y;
    f = __half22float2(*(__half2*)&r.z); acc[4] += f.x; acc[5] += f.y;
    f = __half22float2(*(__half2*)&r.w); acc[6] += f.x; acc[7] += f.y;
}

static __device__ __forceinline__
void unpack_hm(uint4 r0, uint4 r1, float h[8], float m[8]) {
    float2 f;
    f = __half22float2(*(__half2*)&r0.x); h[0] = f.x; m[0] = f.y;
    f = __half22float2(*(__half2*)&r0.y); h[1] = f.x; m[1] = f.y;
    f = __half22float2(*(__half2*)&r0.z); h[2] = f.x; m[2] = f.y;
    f = __half22float2(*(__half2*)&r0.w); h[3] = f.x; m[3] = f.y;
    f = __half22float2(*(__half2*)&r1.x); h[4] = f.x; m[4] = f.y;
    f = __half22float2(*(__half2*)&r1.y); h[5] = f.x; m[5] = f.y;
    f = __half22float2(*(__half2*)&r1.z); h[6] = f.x; m[6] = f.y;
    f = __half22float2(*(__half2*)&r1.w); h[7] = f.x; m[7] = f.y;
}

static __device__ __forceinline__
void gather_h8(const int* __restrict__ csr, const __half* __restrict__ x,
               int e, int e1, float acc[8]) {
    for (; e + 3 < e1; e += 4) {
        int u0 = csr[e], u1 = csr[e + 1], u2 = csr[e + 2], u3 = csr[e + 3];
        uint4 r0 = *(const uint4*)(x + (size_t)u0 * DD);
        uint4 r1 = *(const uint4*)(x + (size_t)u1 * DD);
        uint4 r2 = *(const uint4*)(x + (size_t)u2 * DD);
        uint4 r3 = *(const uint4*)(x + (size_t)u3 * DD);
        acc_h8(r0, acc); acc_h8(r1, acc); acc_h8(r2, acc); acc_h8(r3, acc);
    }
    for (; e < e1; e++) {
        uint4 r = *(const uint4*)(x + (size_t)csr[e] * DD);
        acc_h8(r, acc);
    }
}

// ============================ the mega kernel ===============================

__launch_bounds__(256, 6)
__global__ void mega(Params P) {
    __shared__ __align__(16) float smf[HH * WPITCH + HH];   // 21.5 KB, aliased
    int* smi = (int*)smf;
    const int tid  = threadIdx.x;
    const int gtid = blockIdx.x * 256 + tid;
    const int gstr = gridDim.x * 256;
    int* Bar = P.bar;

    // ---- registration: discover per-XCD block count + populated-XCD count ---
    int xcd = 0, xcnt_ = 1, nx_ = 1, ep = 0;
    if (tid == 0) {
        int xr;
        asm volatile("s_getreg_b32 %0, hwreg(HW_REG_XCC_ID)" : "=s"(xr));
        xcd = xr & 7;
        int pv = __hip_atomic_fetch_add(&Bar[SL_XCNT + xcd], 1,
                                        __ATOMIC_RELAXED, __HIP_MEMORY_SCOPE_AGENT);
        asm volatile("" :: "v"(pv));   // force RMW completion before reg-add
        __hip_atomic_fetch_add(&Bar[SL_REG], 1,
                               __ATOMIC_RELAXED, __HIP_MEMORY_SCOPE_AGENT);
        while (__hip_atomic_load(&Bar[SL_REG], __ATOMIC_RELAXED,
                                 __HIP_MEMORY_SCOPE_AGENT) < NBLK)
            __builtin_amdgcn_s_sleep(2);
        nx_ = 0;
#pragma unroll
        for (int x = 0; x < 8; x++) {
            int c = __hip_atomic_fetch_add(&Bar[SL_XCNT + x], 0,
                                           __ATOMIC_RELAXED, __HIP_MEMORY_SCOPE_AGENT);
            if (x == xcd) xcnt_ = c;
            if (c > 0) nx_++;
        }
    }
    __syncthreads();

    // ---- two-level grid barrier (one L2 wb + one L2 inv per XCD) ----
    auto gsync = [&]() {
        __syncthreads();                 // drains vmcnt: block stores are in L2
        if (tid == 0) {
            ++ep;
            int prev = __hip_atomic_fetch_add(&Bar[SL_XARR + xcd * 16], 1,
                                              __ATOMIC_RELAXED, __HIP_MEMORY_SCOPE_AGENT);
            if (prev == ep * xcnt_ - 1) {
                // XCD master: flush this XCD's L2 (all same-XCD stores)
                __builtin_amdgcn_fence(__ATOMIC_RELEASE, "agent");
                __hip_atomic_fetch_add(&Bar[SL_GAR], 1,
                                       __ATOMIC_RELAXED, __HIP_MEMORY_SCOPE_AGENT);
                while (__hip_atomic_load(&Bar[SL_GAR], __ATOMIC_RELAXED,
                                         __HIP_MEMORY_SCOPE_AGENT) < nx_ * ep)
                    __builtin_amdgcn_s_sleep(1);
                // one L2 (+own L1) invalidate per XCD, before releasing it
                __builtin_amdgcn_fence(__ATOMIC_ACQUIRE, "agent");
                __hip_atomic_store(&Bar[SL_XRDY + xcd * 16], ep,
                                   __ATOMIC_RELAXED, __HIP_MEMORY_SCOPE_AGENT);
            } else {
                while (__hip_atomic_load(&Bar[SL_XRDY + xcd * 16], __ATOMIC_RELAXED,
                                         __HIP_MEMORY_SCOPE_AGENT) < ep)
                    __builtin_amdgcn_s_sleep(1);
                // L2 already fresh (master inv'd); kill only this CU's L1
                asm volatile("buffer_inv" ::: "memory");
            }
        }
        __syncthreads();
    };

    // ---- prologue (no cross-block deps): weight pack + start[N]=E ----
    if (gtid == 0) { P.start_in[P.N] = P.E; P.start_out[P.N] = P.E; }
    for (int t = gtid; t < HH * DD; t += gstr) {
        int j = t >> 3, dd = t & 7;
        P.W12p[j * WPITCH + dd]     = P.W1[dd * HH + j];
        P.W12p[j * WPITCH + 8 + dd] = P.W2[j * DD + dd];
    }
    const float gravv = P.grav[0];

    // ---- phase B: coarse per-chunk histograms (gHist zeroed by memset) ----
    for (int ch = blockIdx.x; ch < P.NC; ch += gridDim.x) {
        int* hIn = smi; int* hOut = smi + 256;
        hIn[tid] = 0; hOut[tid] = 0;
        __syncthreads();
        int lo = ch * CH, hi = min(lo + CH, P.E);
        for (int i = lo + tid; i < hi; i += 256) {
            atomicAdd(&hIn[P.dst[i] >> 9], 1);
            atomicAdd(&hOut[P.src[i] >> 9], 1);
        }
        __syncthreads();
        if (tid < P.NB) {
            int ci = hIn[tid], co = hOut[tid];
            if (ci) atomicAdd(&P.gHistIn[tid], ci);
            if (co) atomicAdd(&P.gHistOut[tid], co);
        }
        __syncthreads();
    }
    gsync();

    // ---- phase C: chunk-level exclusive scan (block 0 only) ----
    if (blockIdx.x == 0) {
#pragma unroll
        for (int dir = 0; dir < 2; dir++) {
            const int* gh_ = dir ? P.gHistOut : P.gHistIn;
            int* cs = dir ? P.cStartOut : P.cStartIn;
            int* cc = dir ? P.cCurOut : P.cCurIn;
            int v = (tid < P.NB) ? gh_[tid] : 0;
            smi[tid] = v;
            __syncthreads();
            for (int off = 1; off < 256; off <<= 1) {
                int t = (tid >= off) ? smi[tid - off] : 0;
                __syncthreads();
                smi[tid] += t;
                __syncthreads();
            }
            if (tid < P.NB) { int ex = smi[tid] - v; cs[tid] = ex; cc[tid] = ex; }
            if (tid == 0) cs[P.NB] = P.E;
            __syncthreads();
        }
    }
    gsync();

    // ---- phase D: partition into per-(chunk, 512-node-bin) runs ----
    for (int vb = blockIdx.x; vb < 2 * P.NC; vb += gridDim.x) {
        int dir = vb >= P.NC;
        int ch  = dir ? vb - P.NC : vb;
        const int* key = dir ? P.src : P.dst;
        const int* pay = dir ? P.dst : P.src;
        int* cCur = dir ? P.cCurOut : P.cCurIn;
        int* Pp   = dir ? P.P_out   : P.P_in;
        int* h = smi;
        h[tid] = 0;
        __syncthreads();
        int lo = ch * CH, hi = min(lo + CH, P.E);
        for (int i = lo + tid; i < hi; i += 256)
            atomicAdd(&h[key[i] >> 9], 1);
        __syncthreads();
        if (tid < P.NB) {
            int c = h[tid];
            h[tid] = c ? atomicAdd(&cCur[tid], c) : 0;
        }
        __syncthreads();
        for (int i = lo + tid; i < hi; i += 256) {
            int k = key[i];
            int pos = atomicAdd(&h[k >> 9], 1);
            Pp[pos] = ((k & 511) << PAYBITS) | pay[i];
        }
        __syncthreads();
    }
    gsync();

    // ---- phase E: fine sort within 512-node bins -> CSR ----
    for (int vb = blockIdx.x; vb < 2 * P.NB; vb += gridDim.x) {
        int dir = vb >= P.NB;
        int b   = dir ? vb - P.NB : vb;
        const int* cStart = dir ? P.cStartOut : P.cStartIn;
        const int* Pp     = dir ? P.P_out     : P.P_in;
        int* start        = dir ? P.start_out : P.start_in;
        int* csr          = dir ? P.csr_out   : P.csr_in;
        int* cnt = smi;              // 512
        int* scn = smi + 512;        // 512
        int* ps  = smi + 1024;       // 256
        int lo = cStart[b], hi = cStart[b + 1];
        cnt[tid] = 0; cnt[tid + 256] = 0;
        __syncthreads();
        for (int i = lo + tid; i < hi; i += 256)
            atomicAdd(&cnt[Pp[i] >> PAYBITS], 1);
        __syncthreads();
        int c0 = cnt[2 * tid], c1 = cnt[2 * tid + 1];
        int pair = c0 + c1;
        ps[tid] = pair;
        __syncthreads();
        for (int off = 1; off < 256; off <<= 1) {
            int t = (tid >= off) ? ps[tid - off] : 0;
            __syncthreads();
            ps[tid] += t;
            __syncthreads();
        }
        int excl = ps[tid] - pair;
        scn[2 * tid] = excl;
        scn[2 * tid + 1] = excl + c0;
        __syncthreads();
#pragma unroll
        for (int k = 0; k < 2; k++) {
            int i = tid + k * 256;
            int base = lo + scn[i];
            int node = (b << 9) + i;
            if (node < P.N) start[node] = base;
            cnt[i] = base;           // reuse as cursor
        }
        __syncthreads();
        for (int i = lo + tid; i < hi; i += 256) {
            int pv = Pp[i];
            int pos = atomicAdd(&cnt[pv >> PAYBITS], 1);
            csr[pos] = pv & PAYMASK;
        }
        __syncthreads();
    }
    gsync();

    // ---- phase F: per-node prep (norms, masses, dHdP) ----
    for (int v = gtid; v < P.N; v += gstr) {
        int ei1 = (v + 1 < P.N) ? P.start_in[v + 1]  : P.E;
        int eo1 = (v + 1 < P.N) ? P.start_out[v + 1] : P.E;
        float din  = (float)(ei1 - P.start_in[v]);
        float dout = (float)(eo1 - P.start_out[v]);
        float av = 1.0f / sqrtf(dout > 0.f ? dout : 1.f);
        float bv = 1.0f / sqrtf(din  > 0.f ? din  : 1.f);
        P.a[v] = av; P.bn[v] = bv;
#pragma unroll
        for (int d = 0; d < DD; d++) {
            float m = P.M[(size_t)v * DD * DD + d * (DD + 1)];
            __half2 hmv;
            hmv.x = __float2half(0.f);
            hmv.y = __float2half(m);
            P.hm[(size_t)v * DD + d] = hmv;
            P.qn[(size_t)v * DD + d] = av * P.q[(size_t)v * DD + d];
            P.out[(size_t)v * 2 * DD + DD + d] = P.p[(size_t)v * DD + d] / m;
        }
    }
    gsync();

    // ---- phase G: agg1 = AggIn(a*q), 2 thr/node ----
    for (int t = gtid; t < 2 * P.N; t += gstr) {
        int v = t >> 1, half = t & 1;
        int e0 = P.start_in[v], e1 = P.start_in[v + 1];
        int mid = e0 + ((e1 - e0) >> 1);
        int e = half ? mid : e0, hiE = half ? e1 : mid;
        float acc[8] = {0.f, 0.f, 0.f, 0.f, 0.f, 0.f, 0.f, 0.f};
        for (; e + 1 < hiE; e += 2) {
            int u0 = P.csr_in[e], u1 = P.csr_in[e + 1];
            const float4* p0 = (const float4*)(P.qn + (size_t)u0 * DD);
            const float4* p1 = (const float4*)(P.qn + (size_t)u1 * DD);
            float4 a0 = p0[0], b0 = p0[1], a1 = p1[0], b1 = p1[1];
            acc[0] += a0.x + a1.x; acc[1] += a0.y + a1.y;
            acc[2] += a0.z + a1.z; acc[3] += a0.w + a1.w;
            acc[4] += b0.x + b1.x; acc[5] += b0.y + b1.y;
            acc[6] += b0.z + b1.z; acc[7] += b0.w + b1.w;
        }
        if (e < hiE) {
            const float4* pp = (const float4*)(P.qn + (size_t)P.csr_in[e] * DD);
            float4 a0 = pp[0], b0 = pp[1];
            acc[0] += a0.x; acc[1] += a0.y; acc[2] += a0.z; acc[3] += a0.w;
            acc[4] += b0.x; acc[5] += b0.y; acc[6] += b0.z; acc[7] += b0.w;
        }
#pragma unroll
        for (int k = 0; k < 8; k++) acc[k] += __shfl_xor(acc[k], 1);
        if (!half) {
            float4* yp = (float4*)(P.agg1 + (size_t)v * DD);
            yp[0] = make_float4(acc[0], acc[1], acc[2], acc[3]);
            yp[1] = make_float4(acc[4], acc[5], acc[6], acc[7]);
        }
    }
    gsync();

    // ---- phase H: MLP forward, 16 lanes/node; weights -> LDS once/block ----
    float* sW  = smf;
    float* sb1 = smf + HH * WPITCH;
    for (int i = tid; i < HH * WPITCH; i += 256) sW[i] = P.W12p[i];
    for (int i = tid; i < HH; i += 256) sb1[i] = P.b1w[i];
    __syncthreads();
    for (int t = gtid; t < 16 * P.N; t += gstr) {
        int v = t >> 4, l16 = t & 15, sub = (t >> 3) & 1, d = t & 7;
        float zl = P.bn[v] * P.agg1[(size_t)v * DD + d];
        float z[DD];
#pragma unroll
        for (int k = 0; k < DD; k++) z[k] = __shfl(zl, k, 16);
        float acc[DD] = {0.f, 0.f, 0.f, 0.f, 0.f, 0.f, 0.f, 0.f};
        for (int c = 0; c < HH / 16; c += 2) {
            int j0 = (c << 4) | l16, j1 = j0 + 16;
            const float4* w0 = (const float4*)(sW + j0 * WPITCH);
            const float4* w1 = (const float4*)(sW + j1 * WPITCH);
            float4 wa0 = w0[0], wb0 = w0[1], va0 = w0[2], vb0 = w0[3];
            float4 wa1 = w1[0], wb1 = w1[1], va1 = w1[2], vb1 = w1[3];
            float ua0 = fmaf(z[1], wa0.y, fmaf(z[0], wa0.x, sb1[j0]));
            ua0 = fmaf(z[3], wa0.w, fmaf(z[2], wa0.z, ua0));
            float ub0 = fmaf(z[5], wb0.y, z[4] * wb0.x);
            ub0 = fmaf(z[7], wb0.w, fmaf(z[6], wb0.z, ub0));
            float ua1 = fmaf(z[1], wa1.y, fmaf(z[0], wa1.x, sb1[j1]));
            ua1 = fmaf(z[3], wa1.w, fmaf(z[2], wa1.z, ua1));
            float ub1 = fmaf(z[5], wb1.y, z[4] * wb1.x);
            ub1 = fmaf(z[7], wb1.w, fmaf(z[6], wb1.z, ub1));
            float h0 = fmaxf(ua0 + ub0, 0.f);
            float h1 = fmaxf(ua1 + ub1, 0.f);
            acc[0] = fmaf(h0, va0.x, acc[0]); acc[1] = fmaf(h0, va0.y, acc[1]);
            acc[2] = fmaf(h0, va0.z, acc[2]); acc[3] = fmaf(h0, va0.w, acc[3]);
            acc[4] = fmaf(h0, vb0.x, acc[4]); acc[5] = fmaf(h0, vb0.y, acc[5]);
            acc[6] = fmaf(h0, vb0.z, acc[6]); acc[7] = fmaf(h0, vb0.w, acc[7]);
            acc[0] = fmaf(h1, va1.x, acc[0]); acc[1] = fmaf(h1, va1.y, acc[1]);
            acc[2] = fmaf(h1, va1.z, acc[2]); acc[3] = fmaf(h1, va1.w, acc[3]);
            acc[4] = fmaf(h1, vb1.x, acc[4]); acc[5] = fmaf(h1, vb1.y, acc[5]);
            acc[6] = fmaf(h1, vb1.z, acc[6]); acc[7] = fmaf(h1, vb1.w, acc[7]);
        }
#pragma unroll
        for (int m = 1; m < 16; m <<= 1)
#pragma unroll
            for (int k = 0; k < DD; k++) acc[k] += __shfl_xor(acc[k], m);
        float yl = acc[0];
#pragma unroll
        for (int k = 1; k < DD; k++) yl = (d == k) ? acc[k] : yl;
        if (!sub) P.ya[(size_t)v * DD + d] = __float2half(P.a[v] * yl);
    }
    gsync();

    // ---- phase I: h = b*AggIn(ya) + b2 + q -> .x halves of hm ----
    for (int t = gtid; t < 2 * P.N; t += gstr) {
        int v = t >> 1, half = t & 1;
        int e0 = P.start_in[v], e1 = P.start_in[v + 1];
        int mid = e0 + ((e1 - e0) >> 1);
        float acc[8] = {0.f, 0.f, 0.f, 0.f, 0.f, 0.f, 0.f, 0.f};
        gather_h8(P.csr_in, P.ya, half ? mid : e0, half ? e1 : mid, acc);
#pragma unroll
        for (int k = 0; k < 8; k++) acc[k] += __shfl_xor(acc[k], 1);
        if (!half) {
            float bv = P.bn[v];
            const float4* qp = (const float4*)(P.q + (size_t)v * DD);
            float4 q0 = qp[0], q1 = qp[1];
            float hq[8] = {q0.x, q0.y, q0.z, q0.w, q1.x, q1.y, q1.z, q1.w};
            __half2* hp = P.hm + (size_t)v * DD;
#pragma unroll
            for (int k = 0; k < DD; k++) {
                float hval = fmaf(bv, acc[k], P.b2w[k] + hq[k]);
                __half2 cur = hp[k];
                cur.x = __float2half(hval);
                hp[k] = cur;
            }
        }
    }
    gsync();

    // ---- phase J: gravity gradient, 4 thr/node (dir x half-range) ----
    for (int t = gtid; t < 4 * P.N; t += gstr) {
        int v = t >> 2, sub = t & 3, dir = sub >> 1, half = sub & 1;
        const uint4* srec = (const uint4*)(P.hm + (size_t)v * DD);
        uint4 s0 = srec[0], s1 = srec[1];
        float hv[8], mv[8];
        unpack_hm(s0, s1, hv, mv);
        const int* start = dir ? P.start_out : P.start_in;
        const int* csr   = dir ? P.csr_out   : P.csr_in;
        int e0 = start[v], e1 = start[v + 1];
        int mid = e0 + ((e1 - e0) >> 1);
        int e = half ? mid : e0, hiE = half ? e1 : mid;
        float coef = -0.5f * gravv;
        float acc[8] = {0.f, 0.f, 0.f, 0.f, 0.f, 0.f, 0.f, 0.f};
        for (; e + 1 < hiE; e += 2) {
            int u0 = csr[e], u1 = csr[e + 1];
            const uint4* r0p = (const uint4*)(P.hm + (size_t)u0 * DD);
            const uint4* r1p = (const uint4*)(P.hm + (size_t)u1 * DD);
            uint4 x0 = r0p[0], x1 = r0p[1], y0 = r1p[0], y1 = r1p[1];
            float hu0[8], mu0[8], hu1[8], mu1[8];
            unpack_hm(x0, x1, hu0, mu0);
            unpack_hm(y0, y1, hu1, mu1);
            float d0[8], d1[8];
            float e20 = 0.f, S0 = 0.f, e21 = 0.f, S1 = 0.f;
#pragma unroll
            for (int k = 0; k < 8; k++) {
                d0[k] = hv[k] - hu0[k];
                d1[k] = hv[k] - hu1[k];
                e20 = fmaf(d0[k], d0[k], e20);
                e21 = fmaf(d1[k], d1[k], e21);
                S0 = fmaf(mv[k], mu0[k], S0);
                S1 = fmaf(mv[k], mu1[k], S1);
            }
            float r0 = rsqrtf(e20), r1 = rsqrtf(e21);
            float c0 = coef * S0 * r0 * r0 * r0;
            float c1 = coef * S1 * r1 * r1 * r1;
#pragma unroll
            for (int k = 0; k < 8; k++)
                acc[k] = fmaf(c0, d0[k], fmaf(c1, d1[k], acc[k]));
        }
        if (e < hiE) {
            int u = csr[e];
            const uint4* rp = (const uint4*)(P.hm + (size_t)u * DD);
            uint4 x0 = rp[0], x1 = rp[1];
            float hu[8], mu[8];
            unpack_hm(x0, x1, hu, mu);
            float df[8];
            float e2 = 0.f, S = 0.f;
#pragma unroll
            for (int k = 0; k < 8; k++) {
                df[k] = hv[k] - hu[k];
                e2 = fmaf(df[k], df[k], e2);
                S = fmaf(mv[k], mu[k], S);
            }
            float r = rsqrtf(e2);
            float c = coef * S * r * r * r;
#pragma unroll
            for (int k = 0; k < 8; k++) acc[k] = fmaf(c, df[k], acc[k]);
        }
#pragma unroll
        for (int k = 0; k < 8; k++) acc[k] += __shfl_xor(acc[k], 1);
#pragma unroll
        for (int k = 0; k < 8; k++) acc[k] += __shfl_xor(acc[k], 2);
        if (sub == 0) {
            float4* gp = (float4*)(P.gh + (size_t)v * DD);
            gp[0] = make_float4(acc[0], acc[1], acc[2], acc[3]);
            gp[1] = make_float4(acc[4], acc[5], acc[6], acc[7]);
            float bv = P.bn[v];
            __half2* bp = (__half2*)(P.bgh + (size_t)v * DD);
            bp[0] = __floats2half2_rn(bv * acc[0], bv * acc[1]);
            bp[1] = __floats2half2_rn(bv * acc[2], bv * acc[3]);
            bp[2] = __floats2half2_rn(bv * acc[4], bv * acc[5]);
            bp[3] = __floats2half2_rn(bv * acc[6], bv * acc[7]);
        }
    }
    gsync();

    // ---- phase K: gq2 = AggOut(bgh), 2 thr/node ----
    for (int t = gtid; t < 2 * P.N; t += gstr) {
        int v = t >> 1, half = t & 1;
        int e0 = P.start_out[v], e1 = P.start_out[v + 1];
        int mid = e0 + ((e1 - e0) >> 1);
        float acc[8] = {0.f, 0.f, 0.f, 0.f, 0.f, 0.f, 0.f, 0.f};
        gather_h8(P.csr_out, P.bgh, half ? mid : e0, half ? e1 : mid, acc);
#pragma unroll
        for (int k = 0; k < 8; k++) acc[k] += __shfl_xor(acc[k], 1);
        if (!half) {
            float4* yp = (float4*)(P.gq2 + (size_t)v * DD);
            yp[0] = make_float4(acc[0], acc[1], acc[2], acc[3]);
            yp[1] = make_float4(acc[4], acc[5], acc[6], acc[7]);
        }
    }
    gsync();

    // ---- phase L: MLP backward (weights still live in LDS from phase H) ----
    for (int t = gtid; t < 16 * P.N; t += gstr) {
        int v = t >> 4, l16 = t & 15, sub = (t >> 3) & 1, d = t & 7;
        float bv = P.bn[v], av = P.a[v];
        float zl = bv * P.agg1[(size_t)v * DD + d];
        float gl = P.gq2[(size_t)v * DD + d];
        float z[DD], gq[DD];
#pragma unroll
        for (int k = 0; k < DD; k++) { z[k] = __shfl(zl, k, 16); gq[k] = __shfl(gl, k, 16); }
        float gz[DD] = {0.f, 0.f, 0.f, 0.f, 0.f, 0.f, 0.f, 0.f};
        for (int c = 0; c < HH / 16; c += 2) {
            int j0 = (c << 4) | l16, j1 = j0 + 16;
            const float4* w0 = (const float4*)(sW + j0 * WPITCH);
            const float4* w1 = (const float4*)(sW + j1 * WPITCH);
            float4 wa0 = w0[0], wb0 = w0[1], va0 = w0[2], vb0 = w0[3];
            float4 wa1 = w1[0], wb1 = w1[1], va1 = w1[2], vb1 = w1[3];
            float ua0 = fmaf(z[1], wa0.y, fmaf(z[0], wa0.x, sb1[j0]));
            ua0 = fmaf(z[3], wa0.w, fmaf(z[2], wa0.z, ua0));
            float ub0 = fmaf(z[5], wb0.y, z[4] * wb0.x);
            ub0 = fmaf(z[7], wb0.w, fmaf(z[6], wb0.z, ub0));
            float ua1 = fmaf(z[1], wa1.y, fmaf(z[0], wa1.x, sb1[j1]));
            ua1 = fmaf(z[3], wa1.w, fmaf(z[2], wa1.z, ua1));
            float ub1 = fmaf(z[5], wb1.y, z[4] * wb1.x);
            ub1 = fmaf(z[7], wb1.w, fmaf(z[6], wb1.z, ub1));
            float u0 = ua0 + ub0, u1 = ua1 + ub1;
            float ga0 = fmaf(gq[1], va0.y, gq[0] * va0.x);
            ga0 = fmaf(gq[3], va0.w, fmaf(gq[2], va0.z, ga0));
            float gb0 = fmaf(gq[5], vb0.y, gq[4] * vb0.x);
            gb0 = fmaf(gq[7], vb0.w, fmaf(gq[6], vb0.z, gb0));
            float ga1 = fmaf(gq[1], va1.y, gq[0] * va1.x);
            ga1 = fmaf(gq[3], va1.w, fmaf(gq[2], va1.z, ga1));
            float gb1 = fmaf(gq[5], vb1.y, gq[4] * vb1.x);
            gb1 = fmaf(gq[7], vb1.w, fmaf(gq[6], vb1.z, gb1));
            float g0 = (u0 > 0.f) ? av * (ga0 + gb0) : 0.f;
            float g1 = (u1 > 0.f) ? av * (ga1 + gb1) : 0.f;
            gz[0] = fmaf(g0, wa0.x, gz[0]); gz[1] = fmaf(g0, wa0.y, gz[1]);
            gz[2] = fmaf(g0, wa0.z, gz[2]); gz[3] = fmaf(g0, wa0.w, gz[3]);
            gz[4] = fmaf(g0, wb0.x, gz[4]); gz[5] = fmaf(g0, wb0.y, gz[5]);
            gz[6] = fmaf(g0, wb0.z, gz[6]); gz[7] = fmaf(g0, wb0.w, gz[7]);
            gz[0] = fmaf(g1, wa1.x, gz[0]); gz[1] = fmaf(g1, wa1.y, gz[1]);
            gz[2] = fmaf(g1, wa1.z, gz[2]); gz[3] = fmaf(g1, wa1.w, gz[3]);
            gz[4] = fmaf(g1, wb1.x, gz[4]); gz[5] = fmaf(g1, wb1.y, gz[5]);
            gz[6] = fmaf(g1, wb1.z, gz[6]); gz[7] = fmaf(g1, wb1.w, gz[7]);
        }
#pragma unroll
        for (int m = 1; m < 16; m <<= 1)
#pragma unroll
            for (int k = 0; k < DD; k++) gz[k] += __shfl_xor(gz[k], m);
        float out_l = gz[0];
#pragma unroll
        for (int k = 1; k < DD; k++) out_l = (d == k) ? gz[k] : out_l;
        if (!sub) P.gz1b[(size_t)v * DD + d] = __float2half(bv * out_l);
    }
    gsync();

    // ---- phase M: out[:, :D] = gh + a * AggOut(gz1b), 2 thr/node ----
    for (int t = gtid; t < 2 * P.N; t += gstr) {
        int v = t >> 1, half = t & 1;
        int e0 = P.start_out[v], e1 = P.start_out[v + 1];
        int mid = e0 + ((e1 - e0) >> 1);
        float acc[8] = {0.f, 0.f, 0.f, 0.f, 0.f, 0.f, 0.f, 0.f};
        gather_h8(P.csr_out, P.gz1b, half ? mid : e0, half ? e1 : mid, acc);
#pragma unroll
        for (int k = 0; k < 8; k++) acc[k] += __shfl_xor(acc[k], 1);
        if (!half) {
            float av = P.a[v];
            const float4* gp = (const float4*)(P.gh + (size_t)v * DD);
            float4 g0 = gp[0], g1 = gp[1];
            float4* op = (float4*)(P.out + (size_t)v * 2 * DD);
            op[0] = make_float4(fmaf(av, acc[0], g0.x), fmaf(av, acc[1], g0.y),
                                fmaf(av, acc[2], g0.z), fmaf(av, acc[3], g0.w));
            op[1] = make_float4(fmaf(av, acc[4], g1.x), fmaf(av, acc[5], g1.y),
                                fmaf(av, acc[6], g1.z), fmaf(av, acc[7], g1.w));
        }
    }
}

// ============================== launch =====================================

extern "C" void kernel_launch(void* const* d_in, const int* in_sizes, int n_in,
                              void* d_out, int out_size, void* d_ws, size_t ws_size,
                              hipStream_t stream) {
    const float* q    = (const float*)d_in[0];
    const float* p    = (const float*)d_in[1];
    const float* M    = (const float*)d_in[2];
    const int*   src  = (const int*)d_in[3];
    const int*   dst  = (const int*)d_in[4];
    const float* W1   = (const float*)d_in[5];
    const float* b1   = (const float*)d_in[6];
    const float* W2   = (const float*)d_in[7];
    const float* b2   = (const float*)d_in[8];
    const float* grav = (const float*)d_in[9];
    float* out = (float*)d_out;

    int N = in_sizes[0] / DD;
    int E = in_sizes[3];
    size_t n = (size_t)N;
    int NB = (N + 511) >> 9;
    int NC = (E + CH - 1) / CH;

    // ---- data region (46N 4-byte words) ----
    float*   ws   = (float*)d_ws;
    float*   a_   = ws;             // N
    float*   b_   = ws + n;         // N
    float*   qn   = ws + 2  * n;    // 8N f32 (reused as gq2 after phase G)
    float*   agg1 = ws + 10 * n;    // 8N f32 (live through bwd)
    float*   gh   = ws + 18 * n;    // 8N f32
    __half2* hm   = (__half2*)(ws + 26 * n);  // 8N half2 (8N words)
    __half*  ya   = (__half*)(ws + 34 * n);   // 8N half (4N words)
    __half*  bgh  = (__half*)(ws + 38 * n);   // 8N half (4N words)
    __half*  gz1b = (__half*)(ws + 42 * n);   // 8N half (4N words)
    float*   gq2  = qn;

    // ---- int region ----
    int* iw        = (int*)(ws + 46 * n);
    int* csr_in    = iw;                       // E
    int* csr_out   = iw + (size_t)E;           // E
    int* start_in  = iw + 2 * (size_t)E;       // N+1
    int* start_out = start_in + n + 1;         // N+1
    int* gHistIn   = start_out + n + 1;        // 256
    int* gHistOut  = gHistIn + 256;            // 256
    int* cStartIn  = gHistOut + 256;           // NB+1
    int* cStartOut = cStartIn + NB + 1;        // NB+1
    int* cCurIn    = cStartOut + NB + 1;       // NB
    int* cCurOut   = cCurIn + NB;              // NB
    int* iwEnd     = cCurOut + NB;
    float* W12p    = (float*)iwEnd;            // HH*WPITCH = 5120 floats
    int* intAfter  = (int*)(W12p + HH * WPITCH);
    // partition scratch: both dirs alias the data region (dead during build)
    int* P_in  = (E <= 16 * (long long)n) ? (int*)ws            : intAfter;
    int* P_out = (E <= 16 * (long long)n) ? (int*)(ws + 16 * n) : intAfter + E;
    int* barp  = (E <= 16 * (long long)n) ? intAfter            : intAfter + 2 * (size_t)E;

    Params prm;
    prm.q = q; prm.p = p; prm.M = M;
    prm.W1 = W1; prm.b1w = b1; prm.W2 = W2; prm.b2w = b2; prm.grav = grav;
    prm.src = src; prm.dst = dst;
    prm.out = out;
    prm.a = a_; prm.bn = b_; prm.qn = qn; prm.agg1 = agg1; prm.gh = gh;
    prm.W12p = W12p;
    prm.hm = hm; prm.ya = ya; prm.bgh = bgh; prm.gz1b = gz1b; prm.gq2 = gq2;
    prm.csr_in = csr_in; prm.csr_out = csr_out;
    prm.start_in = start_in; prm.start_out = start_out;
    prm.gHistIn = gHistIn; prm.gHistOut = gHistOut;
    prm.cStartIn = cStartIn; prm.cStartOut = cStartOut;
    prm.cCurIn = cCurIn; prm.cCurOut = cCurOut;
    prm.P_in = P_in; prm.P_out = P_out;
    prm.bar = barp;
    prm.N = N; prm.E = E; prm.NB = NB; prm.NC = NC;

    // zero the global hists (512 ints) and the barrier state (SL_TOTAL ints)
    hipMemsetAsync(gHistIn, 0, 512 * sizeof(int), stream);
    hipMemsetAsync(barp, 0, SL_TOTAL * sizeof(int), stream);

    mega<<<dim3(NBLK), dim3(256), 0, stream>>>(prm);
}

// Round 7
// 332.333 us; speedup vs baseline: 4.9408x; 4.8699x over previous
//
#include <hip/hip_runtime.h>
#include <hip/hip_fp16.h>

#define DD 8
#define HH 256
#define CH 8192          // edges per chunk in coarse/partition kernels
#define PAYBITS 17       // N <= 131072
#define PAYMASK 0x1FFFF
#define WPITCH 20        // LDS weight row pitch (floats): conflict-free

// Round 1-6 lesson (PMC-verified): persistent-kernel fusion with grid barriers
// is structurally inferior here -- the barrier's agent-scope L2 maintenance
// (wbl2 + full inv per phase) destroys the L2 gather locality the baseline
// relies on; achieved HBM BW pins at ~2.3 TB/s vs ~6 TB/s effective for the
// multi-kernel pipeline. This round: verified 343us multi-kernel structure,
// with the two BARRIER-FREE fusions (per-node deps only):
//   k_agg_node+k_mlp_fwd  -> k_agg_mlp_fwd   (agg1[v] only feeds node v)
//   k_bgh_node+k_mlp_bwd  -> k_bgh_mlp_bwd   (gq2 round-trip eliminated)
// 13 -> 11 dispatches.

// ============================ CSR construction ==============================

__global__ void k_coarse(const int* __restrict__ src, const int* __restrict__ dst,
                         int* __restrict__ gHistIn, int* __restrict__ gHistOut,
                         int NB, int E) {
    __shared__ int hIn[256], hOut[256];
    if (threadIdx.x < 256) { hIn[threadIdx.x] = 0; hOut[threadIdx.x] = 0; }
    __syncthreads();
    int lo = blockIdx.x * CH;
    int hi = min(lo + CH, E);
    for (int i = lo + threadIdx.x; i < hi; i += blockDim.x) {
        atomicAdd(&hIn[dst[i] >> 9], 1);
        atomicAdd(&hOut[src[i] >> 9], 1);
    }
    __syncthreads();
    if (threadIdx.x < NB) {
        int ci = hIn[threadIdx.x], co = hOut[threadIdx.x];
        if (ci) atomicAdd(&gHistIn[threadIdx.x], ci);
        if (co) atomicAdd(&gHistOut[threadIdx.x], co);
    }
}

__global__ void k_cscan(const int* __restrict__ gHistIn, const int* __restrict__ gHistOut,
                        int* __restrict__ cStartIn, int* __restrict__ cStartOut,
                        int* __restrict__ cCurIn, int* __restrict__ cCurOut,
                        int NB, int E) {
    __shared__ int s[256];
#pragma unroll
    for (int dir = 0; dir < 2; dir++) {
        const int* gh = dir ? gHistOut : gHistIn;
        int* cs = dir ? cStartOut : cStartIn;
        int* cc = dir ? cCurOut : cCurIn;
        int v = (threadIdx.x < NB) ? gh[threadIdx.x] : 0;
        s[threadIdx.x] = v;
        __syncthreads();
        for (int off = 1; off < 256; off <<= 1) {
            int t = (threadIdx.x >= off) ? s[threadIdx.x - off] : 0;
            __syncthreads();
            s[threadIdx.x] += t;
            __syncthreads();
        }
        if (threadIdx.x < NB) {
            int ex = s[threadIdx.x] - v;
            cs[threadIdx.x] = ex;
            cc[threadIdx.x] = ex;
        }
        if (threadIdx.x == 0) cs[NB] = E;
        __syncthreads();
    }
}

__global__ void k_part2(const int* __restrict__ src, const int* __restrict__ dst,
                        int* __restrict__ cCurIn, int* __restrict__ cCurOut,
                        int* __restrict__ P_in, int* __restrict__ P_out,
                        int NB, int E) {
    int dir = blockIdx.y;
    const int* key = dir ? src : dst;
    const int* pay = dir ? dst : src;
    int* cCur = dir ? cCurOut : cCurIn;
    int* P    = dir ? P_out   : P_in;
    __shared__ int h[256];
    if (threadIdx.x < 256) h[threadIdx.x] = 0;
    __syncthreads();
    int lo = blockIdx.x * CH;
    int hi = min(lo + CH, E);
    for (int i = lo + threadIdx.x; i < hi; i += blockDim.x)
        atomicAdd(&h[key[i] >> 9], 1);
    __syncthreads();
    if (threadIdx.x < NB) {
        int c = h[threadIdx.x];
        h[threadIdx.x] = c ? atomicAdd(&cCur[threadIdx.x], c) : 0;
    }
    __syncthreads();
    for (int i = lo + threadIdx.x; i < hi; i += blockDim.x) {
        int k = key[i];
        int pos = atomicAdd(&h[k >> 9], 1);
        P[pos] = ((k & 511) << PAYBITS) | pay[i];
    }
}

__launch_bounds__(512)
__global__ void k_fine2(const int* __restrict__ cStartIn, const int* __restrict__ cStartOut,
                        const int* __restrict__ P_in, const int* __restrict__ P_out,
                        int* __restrict__ start_in, int* __restrict__ start_out,
                        int* __restrict__ csr_in, int* __restrict__ csr_out, int N) {
    int dir = blockIdx.y;
    const int* cStart = dir ? cStartOut : cStartIn;
    const int* P      = dir ? P_out     : P_in;
    int* start        = dir ? start_out : start_in;
    int* csr          = dir ? csr_out   : csr_in;
    __shared__ int cnt[512], scn[512];
    int b = blockIdx.x;
    int lo = cStart[b], hi = cStart[b + 1];
    cnt[threadIdx.x] = 0;
    __syncthreads();
    for (int i = lo + threadIdx.x; i < hi; i += 512)
        atomicAdd(&cnt[P[i] >> PAYBITS], 1);
    __syncthreads();
    int own = cnt[threadIdx.x];
    scn[threadIdx.x] = own;
    __syncthreads();
    for (int off = 1; off < 512; off <<= 1) {
        int t = (threadIdx.x >= off) ? scn[threadIdx.x - off] : 0;
        __syncthreads();
        scn[threadIdx.x] += t;
        __syncthreads();
    }
    int base = lo + scn[threadIdx.x] - own;
    int node = (b << 9) + threadIdx.x;
    if (node < N) start[node] = base;
    cnt[threadIdx.x] = base;   // reuse as cursor
    __syncthreads();
    for (int i = lo + threadIdx.x; i < hi; i += 512) {
        int p = P[i];
        int pos = atomicAdd(&cnt[p >> PAYBITS], 1);
        csr[pos] = p & PAYMASK;
    }
}

// ========== per-node prep (norms, masses, dHdP) + weight pack ===============
__global__ void k_prep(const float* __restrict__ q, const float* __restrict__ p,
                       const float* __restrict__ M,
                       const float* __restrict__ W1, const float* __restrict__ W2,
                       float* __restrict__ W12p,
                       int* __restrict__ start_in, int* __restrict__ start_out,
                       float* __restrict__ a, float* __restrict__ b,
                       __half2* __restrict__ hm, float* __restrict__ qn,
                       float* __restrict__ out, int N, int E) {
    int t = blockIdx.x * blockDim.x + threadIdx.x;
    if (t == 0) { start_in[N] = E; start_out[N] = E; }
    if (t < HH * DD) {                      // weight pack
        int j = t >> 3, dd = t & 7;
        W12p[j * WPITCH + dd]     = W1[dd * HH + j];
        W12p[j * WPITCH + 8 + dd] = W2[j * DD + dd];
    }
    int v = t;
    if (v >= N) return;
    int ei1 = (v + 1 < N) ? start_in[v + 1]  : E;
    int eo1 = (v + 1 < N) ? start_out[v + 1] : E;
    float din  = (float)(ei1 - start_in[v]);
    float dout = (float)(eo1 - start_out[v]);
    float av = 1.0f / sqrtf(dout > 0.f ? dout : 1.f);   // norm_src
    float bv = 1.0f / sqrtf(din  > 0.f ? din  : 1.f);   // norm_dst
    a[v] = av; b[v] = bv;
#pragma unroll
    for (int d = 0; d < DD; d++) {
        float m = M[(size_t)v * DD * DD + d * (DD + 1)];
        __half2 hmv;
        hmv.x = __float2half(0.f);
        hmv.y = __float2half(m);
        hm[(size_t)v * DD + d] = hmv;
        qn[(size_t)v * DD + d] = av * q[(size_t)v * DD + d];
        out[(size_t)v * 2 * DD + DD + d] = p[(size_t)v * DD + d] / m;  // dHdP
    }
}

// ------------------- record unpack/accumulate helpers -----------------------
static __device__ __forceinline__
void acc_h8(uint4 r, float acc[8]) {
    float2 f;
    f = __half22float2(*(__half2*)&r.x); acc[0] += f.x; acc[1] += f.y;
    f = __half22float2(*(__half2*)&r.y); acc[2] += f.x; acc[3] += f.y;
    f = __half22float2(*(__half2*)&r.z); acc[4] += f.x; acc[5] += f.y;
    f = __half22float2(*(__half2*)&r.w); acc[6] += f.x; acc[7] += f.y;
}

static __device__ __forceinline__
void unpack_hm(uint4 r0, uint4 r1, float h[8], float m[8]) {
    float2 f;
    f = __half22float2(*(__half2*)&r0.x); h[0] = f.x; m[0] = f.y;
    f = __half22float2(*(__half2*)&r0.y); h[1] = f.x; m[1] = f.y;
    f = __half22float2(*(__half2*)&r0.z); h[2] = f.x; m[2] = f.y;
    f = __half22float2(*(__half2*)&r0.w); h[3] = f.x; m[3] = f.y;
    f = __half22float2(*(__half2*)&r1.x); h[4] = f.x; m[4] = f.y;
    f = __half22float2(*(__half2*)&r1.y); h[5] = f.x; m[5] = f.y;
    f = __half22float2(*(__half2*)&r1.z); h[6] = f.x; m[6] = f.y;
    f = __half22float2(*(__half2*)&r1.w); h[7] = f.x; m[7] = f.y;
}

// gather full half8 records over csr range into acc[8]
static __device__ __forceinline__
void gather_h8(const int* __restrict__ csr, const __half* __restrict__ x,
               int e, int e1, float acc[8]) {
    for (; e + 3 < e1; e += 4) {
        int u0 = csr[e], u1 = csr[e + 1], u2 = csr[e + 2], u3 = csr[e + 3];
        uint4 r0 = *(const uint4*)(x + (size_t)u0 * DD);
        uint4 r1 = *(const uint4*)(x + (size_t)u1 * DD);
        uint4 r2 = *(const uint4*)(x + (size_t)u2 * DD);
        uint4 r3 = *(const uint4*)(x + (size_t)u3 * DD);
        acc_h8(r0, acc); acc_h8(r1, acc); acc_h8(r2, acc); acc_h8(r3, acc);
    }
    for (; e < e1; e++) {
        uint4 r = *(const uint4*)(x + (size_t)csr[e] * DD);
        acc_h8(r, acc);
    }
}

// ===== FUSED: agg1 = AggIn(qn) + MLP forward, 16 lanes/node =====
// agg1[v] feeds only node v's MLP -> same-block fusion, no device barrier.
__launch_bounds__(256)
__global__ void k_agg_mlp_fwd(const int* __restrict__ start, const int* __restrict__ csr,
                              const float* __restrict__ qn,
                              const float* __restrict__ a, const float* __restrict__ b,
                              const float* __restrict__ W12p, const float* __restrict__ b1,
                              float* __restrict__ agg1, __half* __restrict__ ya, int N) {
    __shared__ float sW[HH * WPITCH];
    __shared__ float sb1[HH];
    for (int i = threadIdx.x; i < HH * WPITCH; i += 256) sW[i] = W12p[i];
    for (int i = threadIdx.x; i < HH; i += 256) sb1[i] = b1[i];
    __syncthreads();
    int t = blockIdx.x * 256 + threadIdx.x;
    int v = t >> 4, l16 = t & 15, sub = (t >> 3) & 1, d = t & 7;
    if (v >= N) return;
    int e0 = start[v], e1 = start[v + 1];
    // gather: 16-way split of the in-edge range
    float ag[DD] = {0.f, 0.f, 0.f, 0.f, 0.f, 0.f, 0.f, 0.f};
    for (int e = e0 + l16; e < e1; e += 16) {
        const float4* p0 = (const float4*)(qn + (size_t)csr[e] * DD);
        float4 a0 = p0[0], b0 = p0[1];
        ag[0] += a0.x; ag[1] += a0.y; ag[2] += a0.z; ag[3] += a0.w;
        ag[4] += b0.x; ag[5] += b0.y; ag[6] += b0.z; ag[7] += b0.w;
    }
#pragma unroll
    for (int m = 1; m < 16; m <<= 1)
#pragma unroll
        for (int k = 0; k < DD; k++) ag[k] += __shfl_xor(ag[k], m);
    // persist agg1 (needed by bwd recompute of z)
    if (l16 < 2) {
        float4 val = l16 ? make_float4(ag[4], ag[5], ag[6], ag[7])
                         : make_float4(ag[0], ag[1], ag[2], ag[3]);
        ((float4*)(agg1 + (size_t)v * DD))[l16] = val;
    }
    float bv = b[v];
    float z[DD];
#pragma unroll
    for (int k = 0; k < DD; k++) z[k] = bv * ag[k];
    float acc[DD] = {0.f, 0.f, 0.f, 0.f, 0.f, 0.f, 0.f, 0.f};
    for (int c = 0; c < HH / 16; c += 2) {
        int j0 = (c << 4) | l16, j1 = j0 + 16;
        const float4* w0 = (const float4*)(sW + j0 * WPITCH);
        const float4* w1 = (const float4*)(sW + j1 * WPITCH);
        float4 wa0 = w0[0], wb0 = w0[1], va0 = w0[2], vb0 = w0[3];
        float4 wa1 = w1[0], wb1 = w1[1], va1 = w1[2], vb1 = w1[3];
        float ua0 = fmaf(z[1], wa0.y, fmaf(z[0], wa0.x, sb1[j0]));
        ua0 = fmaf(z[3], wa0.w, fmaf(z[2], wa0.z, ua0));
        float ub0 = fmaf(z[5], wb0.y, z[4] * wb0.x);
        ub0 = fmaf(z[7], wb0.w, fmaf(z[6], wb0.z, ub0));
        float ua1 = fmaf(z[1], wa1.y, fmaf(z[0], wa1.x, sb1[j1]));
        ua1 = fmaf(z[3], wa1.w, fmaf(z[2], wa1.z, ua1));
        float ub1 = fmaf(z[5], wb1.y, z[4] * wb1.x);
        ub1 = fmaf(z[7], wb1.w, fmaf(z[6], wb1.z, ub1));
        float h0 = fmaxf(ua0 + ub0, 0.f);
        float h1 = fmaxf(ua1 + ub1, 0.f);
        acc[0] = fmaf(h0, va0.x, acc[0]); acc[1] = fmaf(h0, va0.y, acc[1]);
        acc[2] = fmaf(h0, va0.z, acc[2]); acc[3] = fmaf(h0, va0.w, acc[3]);
        acc[4] = fmaf(h0, vb0.x, acc[4]); acc[5] = fmaf(h0, vb0.y, acc[5]);
        acc[6] = fmaf(h0, vb0.z, acc[6]); acc[7] = fmaf(h0, vb0.w, acc[7]);
        acc[0] = fmaf(h1, va1.x, acc[0]); acc[1] = fmaf(h1, va1.y, acc[1]);
        acc[2] = fmaf(h1, va1.z, acc[2]); acc[3] = fmaf(h1, va1.w, acc[3]);
        acc[4] = fmaf(h1, vb1.x, acc[4]); acc[5] = fmaf(h1, vb1.y, acc[5]);
        acc[6] = fmaf(h1, vb1.z, acc[6]); acc[7] = fmaf(h1, vb1.w, acc[7]);
    }
#pragma unroll
    for (int m = 1; m < 16; m <<= 1)
#pragma unroll
        for (int k = 0; k < DD; k++) acc[k] += __shfl_xor(acc[k], m);
    float yl = acc[0];
#pragma unroll
    for (int k = 1; k < DD; k++) yl = (d == k) ? acc[k] : yl;
    if (!sub) ya[(size_t)v * DD + d] = __float2half(a[v] * yl);
}

// h = b*AggIn(ya) + b2 + q  -> .x halves of hm records; 2 thr/node
__launch_bounds__(256)
__global__ void k_h_node(const int* __restrict__ start, const int* __restrict__ csr,
                         const __half* __restrict__ ya, const float* __restrict__ b,
                         const float* __restrict__ q, const float* __restrict__ b2,
                         __half2* __restrict__ hm, int N) {
    int t = blockIdx.x * 256 + threadIdx.x;
    int v = t >> 1, half = t & 1;
    if (v >= N) return;
    int e0 = start[v], e1 = start[v + 1];
    int mid = e0 + ((e1 - e0) >> 1);
    float acc[8] = {0.f, 0.f, 0.f, 0.f, 0.f, 0.f, 0.f, 0.f};
    gather_h8(csr, ya, half ? mid : e0, half ? e1 : mid, acc);
#pragma unroll
    for (int k = 0; k < 8; k++) acc[k] += __shfl_xor(acc[k], 1);
    if (!half) {
        float bv = b[v];
        const float4* qp = (const float4*)(q + (size_t)v * DD);
        float4 q0 = qp[0], q1 = qp[1];
        float hq[8] = {q0.x, q0.y, q0.z, q0.w, q1.x, q1.y, q1.z, q1.w};
        __half2* hp = hm + (size_t)v * DD;
#pragma unroll
        for (int k = 0; k < DD; k++) {
            float hval = fmaf(bv, acc[k], b2[k] + hq[k]);
            __half2 cur = hp[k];
            cur.x = __float2half(hval);
            hp[k] = cur;
        }
    }
}

// gravity gradient: 4 threads/node (dir x half-range), full records in-thread
__launch_bounds__(256)
__global__ void k_gh4(const int* __restrict__ start_in, const int* __restrict__ csr_in,
                      const int* __restrict__ start_out, const int* __restrict__ csr_out,
                      const __half2* __restrict__ hm,
                      const float* __restrict__ b, const float* __restrict__ grav,
                      float* __restrict__ gh, __half* __restrict__ bgh, int N) {
    int t = blockIdx.x * 256 + threadIdx.x;
    int v = t >> 2, sub = t & 3, dir = sub >> 1, half = sub & 1;
    if (v >= N) return;
    const uint4* srec = (const uint4*)(hm + (size_t)v * DD);
    uint4 s0 = srec[0], s1 = srec[1];
    float hv[8], mv[8];
    unpack_hm(s0, s1, hv, mv);
    const int* start = dir ? start_out : start_in;
    const int* csr   = dir ? csr_out   : csr_in;
    int e0 = start[v], e1 = start[v + 1];
    int mid = e0 + ((e1 - e0) >> 1);
    int e = half ? mid : e0, hi = half ? e1 : mid;
    float coef = -0.5f * grav[0];
    float acc[8] = {0.f, 0.f, 0.f, 0.f, 0.f, 0.f, 0.f, 0.f};
    for (; e + 1 < hi; e += 2) {
        int u0 = csr[e], u1 = csr[e + 1];
        const uint4* r0p = (const uint4*)(hm + (size_t)u0 * DD);
        const uint4* r1p = (const uint4*)(hm + (size_t)u1 * DD);
        uint4 x0 = r0p[0], x1 = r0p[1], y0 = r1p[0], y1 = r1p[1];
        float hu0[8], mu0[8], hu1[8], mu1[8];
        unpack_hm(x0, x1, hu0, mu0);
        unpack_hm(y0, y1, hu1, mu1);
        float d0[8], d1[8];
        float e20 = 0.f, S0 = 0.f, e21 = 0.f, S1 = 0.f;
#pragma unroll
        for (int k = 0; k < 8; k++) {
            d0[k] = hv[k] - hu0[k];
            d1[k] = hv[k] - hu1[k];
            e20 = fmaf(d0[k], d0[k], e20);
            e21 = fmaf(d1[k], d1[k], e21);
            S0 = fmaf(mv[k], mu0[k], S0);
            S1 = fmaf(mv[k], mu1[k], S1);
        }
        float r0 = rsqrtf(e20), r1 = rsqrtf(e21);
        float c0 = coef * S0 * r0 * r0 * r0;
        float c1 = coef * S1 * r1 * r1 * r1;
#pragma unroll
        for (int k = 0; k < 8; k++)
            acc[k] = fmaf(c0, d0[k], fmaf(c1, d1[k], acc[k]));
    }
    if (e < hi) {
        int u = csr[e];
        const uint4* rp = (const uint4*)(hm + (size_t)u * DD);
        uint4 x0 = rp[0], x1 = rp[1];
        float hu[8], mu[8];
        unpack_hm(x0, x1, hu, mu);
        float df[8];
        float e2 = 0.f, S = 0.f;
#pragma unroll
        for (int k = 0; k < 8; k++) {
            df[k] = hv[k] - hu[k];
            e2 = fmaf(df[k], df[k], e2);
            S = fmaf(mv[k], mu[k], S);
        }
        float r = rsqrtf(e2);
        float c = coef * S * r * r * r;
#pragma unroll
        for (int k = 0; k < 8; k++) acc[k] = fmaf(c, df[k], acc[k]);
    }
    // combine the 4 subset threads (adjacent lanes)
#pragma unroll
    for (int k = 0; k < 8; k++) acc[k] += __shfl_xor(acc[k], 1);
#pragma unroll
    for (int k = 0; k < 8; k++) acc[k] += __shfl_xor(acc[k], 2);
    if (sub == 0) {
        float4* gp = (float4*)(gh + (size_t)v * DD);
        gp[0] = make_float4(acc[0], acc[1], acc[2], acc[3]);
        gp[1] = make_float4(acc[4], acc[5], acc[6], acc[7]);
        float bv = b[v];
        __half2* bp = (__half2*)(bgh + (size_t)v * DD);
        bp[0] = __floats2half2_rn(bv * acc[0], bv * acc[1]);
        bp[1] = __floats2half2_rn(bv * acc[2], bv * acc[3]);
        bp[2] = __floats2half2_rn(bv * acc[4], bv * acc[5]);
        bp[3] = __floats2half2_rn(bv * acc[6], bv * acc[7]);
    }
}

// ===== FUSED: gq = AggOut(bgh) + MLP backward, 16 lanes/node =====
// gq2[v] feeds only node v's MLP-bwd -> fusion removes the gq2 round-trip.
__launch_bounds__(256)
__global__ void k_bgh_mlp_bwd(const int* __restrict__ start, const int* __restrict__ csr,
                              const __half* __restrict__ bgh,
                              const float* __restrict__ agg1,
                              const float* __restrict__ a, const float* __restrict__ b,
                              const float* __restrict__ W12p, const float* __restrict__ b1,
                              __half* __restrict__ gz1b, int N) {
    __shared__ float sW[HH * WPITCH];
    __shared__ float sb1[HH];
    for (int i = threadIdx.x; i < HH * WPITCH; i += 256) sW[i] = W12p[i];
    for (int i = threadIdx.x; i < HH; i += 256) sb1[i] = b1[i];
    __syncthreads();
    int t = blockIdx.x * 256 + threadIdx.x;
    int v = t >> 4, l16 = t & 15, sub = (t >> 3) & 1, d = t & 7;
    if (v >= N) return;
    int e0 = start[v], e1 = start[v + 1];
    // gather AggOut(bgh): 16-way split of the out-edge range
    float gq[DD] = {0.f, 0.f, 0.f, 0.f, 0.f, 0.f, 0.f, 0.f};
    for (int e = e0 + l16; e < e1; e += 16) {
        uint4 r = *(const uint4*)(bgh + (size_t)csr[e] * DD);
        acc_h8(r, gq);
    }
#pragma unroll
    for (int m = 1; m < 16; m <<= 1)
#pragma unroll
        for (int k = 0; k < DD; k++) gq[k] += __shfl_xor(gq[k], m);
    float bv = b[v], av = a[v];
    float zl = bv * agg1[(size_t)v * DD + d];
    float z[DD];
#pragma unroll
    for (int k = 0; k < DD; k++) z[k] = __shfl(zl, k, 16);
    float gz[DD] = {0.f, 0.f, 0.f, 0.f, 0.f, 0.f, 0.f, 0.f};
    for (int c = 0; c < HH / 16; c += 2) {
        int j0 = (c << 4) | l16, j1 = j0 + 16;
        const float4* w0 = (const float4*)(sW + j0 * WPITCH);
        const float4* w1 = (const float4*)(sW + j1 * WPITCH);
        float4 wa0 = w0[0], wb0 = w0[1], va0 = w0[2], vb0 = w0[3];
        float4 wa1 = w1[0], wb1 = w1[1], va1 = w1[2], vb1 = w1[3];
        float ua0 = fmaf(z[1], wa0.y, fmaf(z[0], wa0.x, sb1[j0]));
        ua0 = fmaf(z[3], wa0.w, fmaf(z[2], wa0.z, ua0));
        float ub0 = fmaf(z[5], wb0.y, z[4] * wb0.x);
        ub0 = fmaf(z[7], wb0.w, fmaf(z[6], wb0.z, ub0));
        float ua1 = fmaf(z[1], wa1.y, fmaf(z[0], wa1.x, sb1[j1]));
        ua1 = fmaf(z[3], wa1.w, fmaf(z[2], wa1.z, ua1));
        float ub1 = fmaf(z[5], wb1.y, z[4] * wb1.x);
        ub1 = fmaf(z[7], wb1.w, fmaf(z[6], wb1.z, ub1));
        float u0 = ua0 + ub0, u1 = ua1 + ub1;
        float ga0 = fmaf(gq[1], va0.y, gq[0] * va0.x);
        ga0 = fmaf(gq[3], va0.w, fmaf(gq[2], va0.z, ga0));
        float gb0 = fmaf(gq[5], vb0.y, gq[4] * vb0.x);
        gb0 = fmaf(gq[7], vb0.w, fmaf(gq[6], vb0.z, gb0));
        float ga1 = fmaf(gq[1], va1.y, gq[0] * va1.x);
        ga1 = fmaf(gq[3], va1.w, fmaf(gq[2], va1.z, ga1));
        float gb1 = fmaf(gq[5], vb1.y, gq[4] * vb1.x);
        gb1 = fmaf(gq[7], vb1.w, fmaf(gq[6], vb1.z, gb1));
        float g0 = (u0 > 0.f) ? av * (ga0 + gb0) : 0.f;
        float g1 = (u1 > 0.f) ? av * (ga1 + gb1) : 0.f;
        gz[0] = fmaf(g0, wa0.x, gz[0]); gz[1] = fmaf(g0, wa0.y, gz[1]);
        gz[2] = fmaf(g0, wa0.z, gz[2]); gz[3] = fmaf(g0, wa0.w, gz[3]);
        gz[4] = fmaf(g0, wb0.x, gz[4]); gz[5] = fmaf(g0, wb0.y, gz[5]);
        gz[6] = fmaf(g0, wb0.z, gz[6]); gz[7] = fmaf(g0, wb0.w, gz[7]);
        gz[0] = fmaf(g1, wa1.x, gz[0]); gz[1] = fmaf(g1, wa1.y, gz[1]);
        gz[2] = fmaf(g1, wa1.z, gz[2]); gz[3] = fmaf(g1, wa1.w, gz[3]);
        gz[4] = fmaf(g1, wb1.x, gz[4]); gz[5] = fmaf(g1, wb1.y, gz[5]);
        gz[6] = fmaf(g1, wb1.z, gz[6]); gz[7] = fmaf(g1, wb1.w, gz[7]);
    }
#pragma unroll
    for (int m = 1; m < 16; m <<= 1)
#pragma unroll
        for (int k = 0; k < DD; k++) gz[k] += __shfl_xor(gz[k], m);
    float out_l = gz[0];
#pragma unroll
    for (int k = 1; k < DD; k++) out_l = (d == k) ? gz[k] : out_l;
    if (!sub) gz1b[(size_t)v * DD + d] = __float2half(bv * out_l);
}

// out[:, :D] = gh + a * AggOut(gz1b); 2 thr/node
__launch_bounds__(256)
__global__ void k_out_node(const int* __restrict__ start, const int* __restrict__ csr,
                           const __half* __restrict__ gz1b, const float* __restrict__ gh,
                           const float* __restrict__ a, float* __restrict__ out, int N) {
    int t = blockIdx.x * 256 + threadIdx.x;
    int v = t >> 1, half = t & 1;
    if (v >= N) return;
    int e0 = start[v], e1 = start[v + 1];
    int mid = e0 + ((e1 - e0) >> 1);
    float acc[8] = {0.f, 0.f, 0.f, 0.f, 0.f, 0.f, 0.f, 0.f};
    gather_h8(csr, gz1b, half ? mid : e0, half ? e1 : mid, acc);
#pragma unroll
    for (int k = 0; k < 8; k++) acc[k] += __shfl_xor(acc[k], 1);
    if (!half) {
        float av = a[v];
        const float4* gp = (const float4*)(gh + (size_t)v * DD);
        float4 g0 = gp[0], g1 = gp[1];
        float4* op = (float4*)(out + (size_t)v * 2 * DD);
        op[0] = make_float4(fmaf(av, acc[0], g0.x), fmaf(av, acc[1], g0.y),
                            fmaf(av, acc[2], g0.z), fmaf(av, acc[3], g0.w));
        op[1] = make_float4(fmaf(av, acc[4], g1.x), fmaf(av, acc[5], g1.y),
                            fmaf(av, acc[6], g1.z), fmaf(av, acc[7], g1.w));
    }
}

// ============================== launch =====================================

extern "C" void kernel_launch(void* const* d_in, const int* in_sizes, int n_in,
                              void* d_out, int out_size, void* d_ws, size_t ws_size,
                              hipStream_t stream) {
    const float* q    = (const float*)d_in[0];
    const float* p    = (const float*)d_in[1];
    const float* M    = (const float*)d_in[2];
    const int*   src  = (const int*)d_in[3];
    const int*   dst  = (const int*)d_in[4];
    const float* W1   = (const float*)d_in[5];
    const float* b1   = (const float*)d_in[6];
    const float* W2   = (const float*)d_in[7];
    const float* b2   = (const float*)d_in[8];
    const float* grav = (const float*)d_in[9];
    float* out = (float*)d_out;

    int N = in_sizes[0] / DD;
    int E = in_sizes[3];
    size_t n = (size_t)N;
    int NB = (N + 511) >> 9;

    // ---- data region (46N 4-byte words) ----
    float*   ws   = (float*)d_ws;
    float*   a_   = ws;             // N
    float*   b_   = ws + n;         // N
    float*   qn   = ws + 2  * n;    // 8N f32
    float*   agg1 = ws + 10 * n;    // 8N f32 (live through bwd)
    float*   gh   = ws + 18 * n;    // 8N f32
    __half2* hm   = (__half2*)(ws + 26 * n);  // 8N half2 (8N words)
    __half*  ya   = (__half*)(ws + 34 * n);   // 8N half (4N words)
    __half*  bgh  = (__half*)(ws + 38 * n);   // 8N half (4N words)
    __half*  gz1b = (__half*)(ws + 42 * n);   // 8N half (4N words)

    // ---- int region ----
    int* iw        = (int*)(ws + 46 * n);
    int* csr_in    = iw;                       // E
    int* csr_out   = iw + (size_t)E;           // E
    int* start_in  = iw + 2 * (size_t)E;       // N+1
    int* start_out = start_in + n + 1;         // N+1
    int* gHistIn   = start_out + n + 1;        // 256
    int* gHistOut  = gHistIn + 256;            // 256
    int* cStartIn  = gHistOut + 256;           // NB+1
    int* cStartOut = cStartIn + NB + 1;        // NB+1
    int* cCurIn    = cStartOut + NB + 1;       // NB
    int* cCurOut   = cCurIn + NB;              // NB
    int* iwEnd     = cCurOut + NB;
    float* W12p    = (float*)iwEnd;            // HH*WPITCH = 5120 floats
    int* intAfter  = (int*)(W12p + HH * WPITCH);
    // partition scratch: both dirs alias the data region (dead during build)
    int* P_in  = (E <= 16 * (long long)n) ? (int*)ws            : intAfter;
    int* P_out = (E <= 16 * (long long)n) ? (int*)(ws + 16 * n) : intAfter + E;

    hipMemsetAsync(gHistIn, 0, 512 * sizeof(int), stream);

    const int tb = 256;
    int gbN  = (N + tb - 1) / tb;
    int gb2  = (2 * N + tb - 1) / tb;          // 2 threads/node
    int gb4  = (4 * N + tb - 1) / tb;          // 4 threads/node
    int gb16 = (int)((16 * n + tb - 1) / tb);  // 16 lanes/node
    int gbC  = (E + CH - 1) / CH;

    // CSR build
    k_coarse  <<<gbC, tb, 0, stream>>>(src, dst, gHistIn, gHistOut, NB, E);
    k_cscan   <<<1, 256, 0, stream>>>(gHistIn, gHistOut, cStartIn, cStartOut,
                                      cCurIn, cCurOut, NB, E);
    k_part2   <<<dim3(gbC, 2), tb, 0, stream>>>(src, dst, cCurIn, cCurOut,
                                                P_in, P_out, NB, E);
    k_fine2   <<<dim3(NB, 2), 512, 0, stream>>>(cStartIn, cStartOut, P_in, P_out,
                                                start_in, start_out, csr_in, csr_out, N);
    k_prep    <<<gbN, tb, 0, stream>>>(q, p, M, W1, W2, W12p, start_in, start_out,
                                       a_, b_, hm, qn, out, N, E);

    // forward: [agg1 = AggIn(a*q)] + [ya = a*(relu((b*agg1)@W1+b1)@W2)] fused
    k_agg_mlp_fwd<<<gb16, tb, 0, stream>>>(start_in, csr_in, qn, a_, b_,
                                           W12p, b1, agg1, ya, N);
    // h = b * AggIn(ya) + b2 + q  -> .x halves of hm
    k_h_node  <<<gb2, tb, 0, stream>>>(start_in, csr_in, ya, b_, q, b2, hm, N);
    // gravity gradient (4 threads/node, full records in-thread)
    k_gh4     <<<gb4, tb, 0, stream>>>(start_in, csr_in, start_out, csr_out,
                                       hm, b_, grav, gh, bgh, N);
    // [gq = AggOut(bgh)] + [gz1b = b*((a*(gq@W2^T)*relu')@W1^T)] fused
    k_bgh_mlp_bwd<<<gb16, tb, 0, stream>>>(start_out, csr_out, bgh, agg1, a_, b_,
                                           W12p, b1, gz1b, N);
    // dHdQ = gh + a * AggOut(gz1b)
    k_out_node<<<gb2, tb, 0, stream>>>(start_out, csr_out, gz1b, gh, a_, out, N);
}

// Round 8
// 328.512 us; speedup vs baseline: 4.9983x; 1.0116x over previous
//
#include <hip/hip_runtime.h>
#include <hip/hip_fp16.h>

#define DD 8
#define HH 256
#define CH 8192          // edges per chunk in coarse/partition kernels
#define PAYBITS 17       // N <= 131072
#define PAYMASK 0x1FFFF
#define WHPITCH 12       // fp16 weight row pitch in uints (48B: b128-aligned, 2-way banks)

// R7 PMC: k_bgh_mlp_bwd 48.7us == LDS-bound (64 ds_read_b128 + 64 bpermute
// per wave ~ 1150 LDS cyc x 98 waves/CU ~= 47us). R8: halve weight-read bytes
// (fp16 weights, one b128 per W1/W2 row), v_dot2_f32_f16 for dot parts,
// fp16 qn records (halve fwd gather bytes). Everything else identical to R7.

typedef _Float16 h2f __attribute__((ext_vector_type(2)));

static __device__ __forceinline__ float2 u2f(unsigned w) {
    __half2 h = __builtin_bit_cast(__half2, w);
    return __half22float2(h);
}
static __device__ __forceinline__ float dot2u(unsigned w, h2f z, float c) {
#if __has_builtin(__builtin_amdgcn_fdot2)
    return __builtin_amdgcn_fdot2(__builtin_bit_cast(h2f, w), z, c, false);
#else
    float2 f = u2f(w);
    return fmaf(f.y, (float)z[1], fmaf(f.x, (float)z[0], c));
#endif
}
static __device__ __forceinline__ h2f pkh(float a, float b) {
    h2f r; r[0] = (_Float16)a; r[1] = (_Float16)b; return r;
}

// ============================ CSR construction ==============================

__global__ void k_coarse(const int* __restrict__ src, const int* __restrict__ dst,
                         int* __restrict__ gHistIn, int* __restrict__ gHistOut,
                         int NB, int E) {
    __shared__ int hIn[256], hOut[256];
    if (threadIdx.x < 256) { hIn[threadIdx.x] = 0; hOut[threadIdx.x] = 0; }
    __syncthreads();
    int lo = blockIdx.x * CH;
    int hi = min(lo + CH, E);
    for (int i = lo + threadIdx.x; i < hi; i += blockDim.x) {
        atomicAdd(&hIn[dst[i] >> 9], 1);
        atomicAdd(&hOut[src[i] >> 9], 1);
    }
    __syncthreads();
    if (threadIdx.x < NB) {
        int ci = hIn[threadIdx.x], co = hOut[threadIdx.x];
        if (ci) atomicAdd(&gHistIn[threadIdx.x], ci);
        if (co) atomicAdd(&gHistOut[threadIdx.x], co);
    }
}

__global__ void k_cscan(const int* __restrict__ gHistIn, const int* __restrict__ gHistOut,
                        int* __restrict__ cStartIn, int* __restrict__ cStartOut,
                        int* __restrict__ cCurIn, int* __restrict__ cCurOut,
                        int NB, int E) {
    __shared__ int s[256];
#pragma unroll
    for (int dir = 0; dir < 2; dir++) {
        const int* gh = dir ? gHistOut : gHistIn;
        int* cs = dir ? cStartOut : cStartIn;
        int* cc = dir ? cCurOut : cCurIn;
        int v = (threadIdx.x < NB) ? gh[threadIdx.x] : 0;
        s[threadIdx.x] = v;
        __syncthreads();
        for (int off = 1; off < 256; off <<= 1) {
            int t = (threadIdx.x >= off) ? s[threadIdx.x - off] : 0;
            __syncthreads();
            s[threadIdx.x] += t;
            __syncthreads();
        }
        if (threadIdx.x < NB) {
            int ex = s[threadIdx.x] - v;
            cs[threadIdx.x] = ex;
            cc[threadIdx.x] = ex;
        }
        if (threadIdx.x == 0) cs[NB] = E;
        __syncthreads();
    }
}

__global__ void k_part2(const int* __restrict__ src, const int* __restrict__ dst,
                        int* __restrict__ cCurIn, int* __restrict__ cCurOut,
                        int* __restrict__ P_in, int* __restrict__ P_out,
                        int NB, int E) {
    int dir = blockIdx.y;
    const int* key = dir ? src : dst;
    const int* pay = dir ? dst : src;
    int* cCur = dir ? cCurOut : cCurIn;
    int* P    = dir ? P_out   : P_in;
    __shared__ int h[256];
    if (threadIdx.x < 256) h[threadIdx.x] = 0;
    __syncthreads();
    int lo = blockIdx.x * CH;
    int hi = min(lo + CH, E);
    for (int i = lo + threadIdx.x; i < hi; i += blockDim.x)
        atomicAdd(&h[key[i] >> 9], 1);
    __syncthreads();
    if (threadIdx.x < NB) {
        int c = h[threadIdx.x];
        h[threadIdx.x] = c ? atomicAdd(&cCur[threadIdx.x], c) : 0;
    }
    __syncthreads();
    for (int i = lo + threadIdx.x; i < hi; i += blockDim.x) {
        int k = key[i];
        int pos = atomicAdd(&h[k >> 9], 1);
        P[pos] = ((k & 511) << PAYBITS) | pay[i];
    }
}

__launch_bounds__(512)
__global__ void k_fine2(const int* __restrict__ cStartIn, const int* __restrict__ cStartOut,
                        const int* __restrict__ P_in, const int* __restrict__ P_out,
                        int* __restrict__ start_in, int* __restrict__ start_out,
                        int* __restrict__ csr_in, int* __restrict__ csr_out, int N) {
    int dir = blockIdx.y;
    const int* cStart = dir ? cStartOut : cStartIn;
    const int* P      = dir ? P_out     : P_in;
    int* start        = dir ? start_out : start_in;
    int* csr          = dir ? csr_out   : csr_in;
    __shared__ int cnt[512], scn[512];
    int b = blockIdx.x;
    int lo = cStart[b], hi = cStart[b + 1];
    cnt[threadIdx.x] = 0;
    __syncthreads();
    for (int i = lo + threadIdx.x; i < hi; i += 512)
        atomicAdd(&cnt[P[i] >> PAYBITS], 1);
    __syncthreads();
    int own = cnt[threadIdx.x];
    scn[threadIdx.x] = own;
    __syncthreads();
    for (int off = 1; off < 512; off <<= 1) {
        int t = (threadIdx.x >= off) ? scn[threadIdx.x - off] : 0;
        __syncthreads();
        scn[threadIdx.x] += t;
        __syncthreads();
    }
    int base = lo + scn[threadIdx.x] - own;
    int node = (b << 9) + threadIdx.x;
    if (node < N) start[node] = base;
    cnt[threadIdx.x] = base;   // reuse as cursor
    __syncthreads();
    for (int i = lo + threadIdx.x; i < hi; i += 512) {
        int p = P[i];
        int pos = atomicAdd(&cnt[p >> PAYBITS], 1);
        csr[pos] = p & PAYMASK;
    }
}

// ========== per-node prep (norms, masses, dHdP) + fp16 weight pack ==========
__global__ void k_prep(const float* __restrict__ q, const float* __restrict__ p,
                       const float* __restrict__ M,
                       const float* __restrict__ W1, const float* __restrict__ W2,
                       unsigned* __restrict__ W12h,
                       int* __restrict__ start_in, int* __restrict__ start_out,
                       float* __restrict__ a, float* __restrict__ b,
                       __half2* __restrict__ hm, __half* __restrict__ qn,
                       float* __restrict__ out, int N, int E) {
    int t = blockIdx.x * blockDim.x + threadIdx.x;
    if (t == 0) { start_in[N] = E; start_out[N] = E; }
    if (t < HH * 8) {                       // fp16 weight pack: row j = 12 uints
        int j = t >> 3, k = t & 7;
        __half2 hh;
        if (k < 4) {                        // W1 row j (W1 is [D,H], need col j)
            hh.x = __float2half(W1[(2 * k) * HH + j]);
            hh.y = __float2half(W1[(2 * k + 1) * HH + j]);
            W12h[j * WHPITCH + k] = *(unsigned*)&hh;
        } else {                            // W2 row j ([H,D])
            int kk = k - 4;
            hh.x = __float2half(W2[j * DD + 2 * kk]);
            hh.y = __float2half(W2[j * DD + 2 * kk + 1]);
            W12h[j * WHPITCH + 4 + kk] = *(unsigned*)&hh;
        }
    }
    int v = t;
    if (v >= N) return;
    int ei1 = (v + 1 < N) ? start_in[v + 1]  : E;
    int eo1 = (v + 1 < N) ? start_out[v + 1] : E;
    float din  = (float)(ei1 - start_in[v]);
    float dout = (float)(eo1 - start_out[v]);
    float av = 1.0f / sqrtf(dout > 0.f ? dout : 1.f);   // norm_src
    float bv = 1.0f / sqrtf(din  > 0.f ? din  : 1.f);   // norm_dst
    a[v] = av; b[v] = bv;
#pragma unroll
    for (int d = 0; d < DD; d++) {
        float m = M[(size_t)v * DD * DD + d * (DD + 1)];
        __half2 hmv;
        hmv.x = __float2half(0.f);
        hmv.y = __float2half(m);
        hm[(size_t)v * DD + d] = hmv;
        qn[(size_t)v * DD + d] = __float2half(av * q[(size_t)v * DD + d]);
        out[(size_t)v * 2 * DD + DD + d] = p[(size_t)v * DD + d] / m;  // dHdP
    }
}

// ------------------- record unpack/accumulate helpers -----------------------
static __device__ __forceinline__
void acc_h8(uint4 r, float acc[8]) {
    float2 f;
    f = __half22float2(*(__half2*)&r.x); acc[0] += f.x; acc[1] += f.y;
    f = __half22float2(*(__half2*)&r.y); acc[2] += f.x; acc[3] += f.y;
    f = __half22float2(*(__half2*)&r.z); acc[4] += f.x; acc[5] += f.y;
    f = __half22float2(*(__half2*)&r.w); acc[6] += f.x; acc[7] += f.y;
}

static __device__ __forceinline__
void unpack_hm(uint4 r0, uint4 r1, float h[8], float m[8]) {
    float2 f;
    f = __half22float2(*(__half2*)&r0.x); h[0] = f.x; m[0] = f.y;
    f = __half22float2(*(__half2*)&r0.y); h[1] = f.x; m[1] = f.y;
    f = __half22float2(*(__half2*)&r0.z); h[2] = f.x; m[2] = f.y;
    f = __half22float2(*(__half2*)&r0.w); h[3] = f.x; m[3] = f.y;
    f = __half22float2(*(__half2*)&r1.x); h[4] = f.x; m[4] = f.y;
    f = __half22float2(*(__half2*)&r1.y); h[5] = f.x; m[5] = f.y;
    f = __half22float2(*(__half2*)&r1.z); h[6] = f.x; m[6] = f.y;
    f = __half22float2(*(__half2*)&r1.w); h[7] = f.x; m[7] = f.y;
}

// gather full half8 records over csr range into acc[8]
static __device__ __forceinline__
void gather_h8(const int* __restrict__ csr, const __half* __restrict__ x,
               int e, int e1, float acc[8]) {
    for (; e + 3 < e1; e += 4) {
        int u0 = csr[e], u1 = csr[e + 1], u2 = csr[e + 2], u3 = csr[e + 3];
        uint4 r0 = *(const uint4*)(x + (size_t)u0 * DD);
        uint4 r1 = *(const uint4*)(x + (size_t)u1 * DD);
        uint4 r2 = *(const uint4*)(x + (size_t)u2 * DD);
        uint4 r3 = *(const uint4*)(x + (size_t)u3 * DD);
        acc_h8(r0, acc); acc_h8(r1, acc); acc_h8(r2, acc); acc_h8(r3, acc);
    }
    for (; e < e1; e++) {
        uint4 r = *(const uint4*)(x + (size_t)csr[e] * DD);
        acc_h8(r, acc);
    }
}

// ===== FUSED: agg1 = AggIn(qn) + MLP forward, 16 lanes/node, fp16 W =====
__launch_bounds__(256)
__global__ void k_agg_mlp_fwd(const int* __restrict__ start, const int* __restrict__ csr,
                              const __half* __restrict__ qn,
                              const float* __restrict__ a, const float* __restrict__ b,
                              const unsigned* __restrict__ W12h, const float* __restrict__ b1,
                              float* __restrict__ agg1, __half* __restrict__ ya, int N) {
    __shared__ unsigned sWH[HH * WHPITCH];   // 12 KB
    __shared__ float sb1[HH];
    for (int i = threadIdx.x; i < HH * WHPITCH; i += 256) sWH[i] = W12h[i];
    for (int i = threadIdx.x; i < HH; i += 256) sb1[i] = b1[i];
    __syncthreads();
    int t = blockIdx.x * 256 + threadIdx.x;
    int v = t >> 4, l16 = t & 15, sub = (t >> 3) & 1, d = t & 7;
    if (v >= N) return;
    int e0 = start[v], e1 = start[v + 1];
    // gather fp16 qn records: 16-way split of the in-edge range
    float ag[DD] = {0.f, 0.f, 0.f, 0.f, 0.f, 0.f, 0.f, 0.f};
    for (int e = e0 + l16; e < e1; e += 16) {
        uint4 r = *(const uint4*)(qn + (size_t)csr[e] * DD);
        acc_h8(r, ag);
    }
#pragma unroll
    for (int m = 1; m < 16; m <<= 1)
#pragma unroll
        for (int k = 0; k < DD; k++) ag[k] += __shfl_xor(ag[k], m);
    // persist agg1 f32 (needed by bwd recompute of z)
    if (l16 < 2) {
        float4 val = l16 ? make_float4(ag[4], ag[5], ag[6], ag[7])
                         : make_float4(ag[0], ag[1], ag[2], ag[3]);
        ((float4*)(agg1 + (size_t)v * DD))[l16] = val;
    }
    float bv = b[v];
    h2f zh[4];
#pragma unroll
    for (int k = 0; k < 4; k++) zh[k] = pkh(bv * ag[2 * k], bv * ag[2 * k + 1]);
    float acc[DD] = {0.f, 0.f, 0.f, 0.f, 0.f, 0.f, 0.f, 0.f};
    for (int c = 0; c < HH / 16; c += 2) {
        int j0 = (c << 4) | l16, j1 = j0 + 16;
        const uint4* r0 = (const uint4*)(sWH + j0 * WHPITCH);
        const uint4* r1 = (const uint4*)(sWH + j1 * WHPITCH);
        uint4 w1a = r0[0], w2a = r0[1];
        uint4 w1b = r1[0], w2b = r1[1];
        float u0 = sb1[j0], u1 = sb1[j1];
        u0 = dot2u(w1a.x, zh[0], u0); u0 = dot2u(w1a.y, zh[1], u0);
        u0 = dot2u(w1a.z, zh[2], u0); u0 = dot2u(w1a.w, zh[3], u0);
        u1 = dot2u(w1b.x, zh[0], u1); u1 = dot2u(w1b.y, zh[1], u1);
        u1 = dot2u(w1b.z, zh[2], u1); u1 = dot2u(w1b.w, zh[3], u1);
        float h0 = fmaxf(u0, 0.f);
        float h1 = fmaxf(u1, 0.f);
        float2 f;
        f = u2f(w2a.x); acc[0] = fmaf(h0, f.x, acc[0]); acc[1] = fmaf(h0, f.y, acc[1]);
        f = u2f(w2a.y); acc[2] = fmaf(h0, f.x, acc[2]); acc[3] = fmaf(h0, f.y, acc[3]);
        f = u2f(w2a.z); acc[4] = fmaf(h0, f.x, acc[4]); acc[5] = fmaf(h0, f.y, acc[5]);
        f = u2f(w2a.w); acc[6] = fmaf(h0, f.x, acc[6]); acc[7] = fmaf(h0, f.y, acc[7]);
        f = u2f(w2b.x); acc[0] = fmaf(h1, f.x, acc[0]); acc[1] = fmaf(h1, f.y, acc[1]);
        f = u2f(w2b.y); acc[2] = fmaf(h1, f.x, acc[2]); acc[3] = fmaf(h1, f.y, acc[3]);
        f = u2f(w2b.z); acc[4] = fmaf(h1, f.x, acc[4]); acc[5] = fmaf(h1, f.y, acc[5]);
        f = u2f(w2b.w); acc[6] = fmaf(h1, f.x, acc[6]); acc[7] = fmaf(h1, f.y, acc[7]);
    }
#pragma unroll
    for (int m = 1; m < 16; m <<= 1)
#pragma unroll
        for (int k = 0; k < DD; k++) acc[k] += __shfl_xor(acc[k], m);
    float yl = acc[0];
#pragma unroll
    for (int k = 1; k < DD; k++) yl = (d == k) ? acc[k] : yl;
    if (!sub) ya[(size_t)v * DD + d] = __float2half(a[v] * yl);
}

// h = b*AggIn(ya) + b2 + q  -> .x halves of hm records; 2 thr/node
__launch_bounds__(256)
__global__ void k_h_node(const int* __restrict__ start, const int* __restrict__ csr,
                         const __half* __restrict__ ya, const float* __restrict__ b,
                         const float* __restrict__ q, const float* __restrict__ b2,
                         __half2* __restrict__ hm, int N) {
    int t = blockIdx.x * 256 + threadIdx.x;
    int v = t >> 1, half = t & 1;
    if (v >= N) return;
    int e0 = start[v], e1 = start[v + 1];
    int mid = e0 + ((e1 - e0) >> 1);
    float acc[8] = {0.f, 0.f, 0.f, 0.f, 0.f, 0.f, 0.f, 0.f};
    gather_h8(csr, ya, half ? mid : e0, half ? e1 : mid, acc);
#pragma unroll
    for (int k = 0; k < 8; k++) acc[k] += __shfl_xor(acc[k], 1);
    if (!half) {
        float bv = b[v];
        const float4* qp = (const float4*)(q + (size_t)v * DD);
        float4 q0 = qp[0], q1 = qp[1];
        float hq[8] = {q0.x, q0.y, q0.z, q0.w, q1.x, q1.y, q1.z, q1.w};
        __half2* hp = hm + (size_t)v * DD;
#pragma unroll
        for (int k = 0; k < DD; k++) {
            float hval = fmaf(bv, acc[k], b2[k] + hq[k]);
            __half2 cur = hp[k];
            cur.x = __float2half(hval);
            hp[k] = cur;
        }
    }
}

// gravity gradient: 4 threads/node (dir x half-range), full records in-thread
__launch_bounds__(256)
__global__ void k_gh4(const int* __restrict__ start_in, const int* __restrict__ csr_in,
                      const int* __restrict__ start_out, const int* __restrict__ csr_out,
                      const __half2* __restrict__ hm,
                      const float* __restrict__ b, const float* __restrict__ grav,
                      float* __restrict__ gh, __half* __restrict__ bgh, int N) {
    int t = blockIdx.x * 256 + threadIdx.x;
    int v = t >> 2, sub = t & 3, dir = sub >> 1, half = sub & 1;
    if (v >= N) return;
    const uint4* srec = (const uint4*)(hm + (size_t)v * DD);
    uint4 s0 = srec[0], s1 = srec[1];
    float hv[8], mv[8];
    unpack_hm(s0, s1, hv, mv);
    const int* start = dir ? start_out : start_in;
    const int* csr   = dir ? csr_out   : csr_in;
    int e0 = start[v], e1 = start[v + 1];
    int mid = e0 + ((e1 - e0) >> 1);
    int e = half ? mid : e0, hi = half ? e1 : mid;
    float coef = -0.5f * grav[0];
    float acc[8] = {0.f, 0.f, 0.f, 0.f, 0.f, 0.f, 0.f, 0.f};
    for (; e + 1 < hi; e += 2) {
        int u0 = csr[e], u1 = csr[e + 1];
        const uint4* r0p = (const uint4*)(hm + (size_t)u0 * DD);
        const uint4* r1p = (const uint4*)(hm + (size_t)u1 * DD);
        uint4 x0 = r0p[0], x1 = r0p[1], y0 = r1p[0], y1 = r1p[1];
        float hu0[8], mu0[8], hu1[8], mu1[8];
        unpack_hm(x0, x1, hu0, mu0);
        unpack_hm(y0, y1, hu1, mu1);
        float d0[8], d1[8];
        float e20 = 0.f, S0 = 0.f, e21 = 0.f, S1 = 0.f;
#pragma unroll
        for (int k = 0; k < 8; k++) {
            d0[k] = hv[k] - hu0[k];
            d1[k] = hv[k] - hu1[k];
            e20 = fmaf(d0[k], d0[k], e20);
            e21 = fmaf(d1[k], d1[k], e21);
            S0 = fmaf(mv[k], mu0[k], S0);
            S1 = fmaf(mv[k], mu1[k], S1);
        }
        float r0 = rsqrtf(e20), r1 = rsqrtf(e21);
        float c0 = coef * S0 * r0 * r0 * r0;
        float c1 = coef * S1 * r1 * r1 * r1;
#pragma unroll
        for (int k = 0; k < 8; k++)
            acc[k] = fmaf(c0, d0[k], fmaf(c1, d1[k], acc[k]));
    }
    if (e < hi) {
        int u = csr[e];
        const uint4* rp = (const uint4*)(hm + (size_t)u * DD);
        uint4 x0 = rp[0], x1 = rp[1];
        float hu[8], mu[8];
        unpack_hm(x0, x1, hu, mu);
        float df[8];
        float e2 = 0.f, S = 0.f;
#pragma unroll
        for (int k = 0; k < 8; k++) {
            df[k] = hv[k] - hu[k];
            e2 = fmaf(df[k], df[k], e2);
            S = fmaf(mv[k], mu[k], S);
        }
        float r = rsqrtf(e2);
        float c = coef * S * r * r * r;
#pragma unroll
        for (int k = 0; k < 8; k++) acc[k] = fmaf(c, df[k], acc[k]);
    }
    // combine the 4 subset threads (adjacent lanes)
#pragma unroll
    for (int k = 0; k < 8; k++) acc[k] += __shfl_xor(acc[k], 1);
#pragma unroll
    for (int k = 0; k < 8; k++) acc[k] += __shfl_xor(acc[k], 2);
    if (sub == 0) {
        float4* gp = (float4*)(gh + (size_t)v * DD);
        gp[0] = make_float4(acc[0], acc[1], acc[2], acc[3]);
        gp[1] = make_float4(acc[4], acc[5], acc[6], acc[7]);
        float bv = b[v];
        __half2* bp = (__half2*)(bgh + (size_t)v * DD);
        bp[0] = __floats2half2_rn(bv * acc[0], bv * acc[1]);
        bp[1] = __floats2half2_rn(bv * acc[2], bv * acc[3]);
        bp[2] = __floats2half2_rn(bv * acc[4], bv * acc[5]);
        bp[3] = __floats2half2_rn(bv * acc[6], bv * acc[7]);
    }
}

// ===== FUSED: gq = AggOut(bgh) + MLP backward, 16 lanes/node, fp16 W =====
__launch_bounds__(256)
__global__ void k_bgh_mlp_bwd(const int* __restrict__ start, const int* __restrict__ csr,
                              const __half* __restrict__ bgh,
                              const float* __restrict__ agg1,
                              const float* __restrict__ a, const float* __restrict__ b,
                              const unsigned* __restrict__ W12h, const float* __restrict__ b1,
                              __half* __restrict__ gz1b, int N) {
    __shared__ unsigned sWH[HH * WHPITCH];   // 12 KB
    __shared__ float sb1[HH];
    for (int i = threadIdx.x; i < HH * WHPITCH; i += 256) sWH[i] = W12h[i];
    for (int i = threadIdx.x; i < HH; i += 256) sb1[i] = b1[i];
    __syncthreads();
    int t = blockIdx.x * 256 + threadIdx.x;
    int v = t >> 4, l16 = t & 15, sub = (t >> 3) & 1, d = t & 7;
    if (v >= N) return;
    int e0 = start[v], e1 = start[v + 1];
    // gather AggOut(bgh): 16-way split of the out-edge range
    float gq[DD] = {0.f, 0.f, 0.f, 0.f, 0.f, 0.f, 0.f, 0.f};
    for (int e = e0 + l16; e < e1; e += 16) {
        uint4 r = *(const uint4*)(bgh + (size_t)csr[e] * DD);
        acc_h8(r, gq);
    }
#pragma unroll
    for (int m = 1; m < 16; m <<= 1)
#pragma unroll
        for (int k = 0; k < DD; k++) gq[k] += __shfl_xor(gq[k], m);
    float bv = b[v], av = a[v];
    float zl = bv * agg1[(size_t)v * DD + d];
    h2f zh[4], gqh[4];
#pragma unroll
    for (int k = 0; k < 4; k++) {
        float za = __shfl(zl, 2 * k, 16), zb = __shfl(zl, 2 * k + 1, 16);
        zh[k] = pkh(za, zb);
        gqh[k] = pkh(gq[2 * k], gq[2 * k + 1]);
    }
    float gz[DD] = {0.f, 0.f, 0.f, 0.f, 0.f, 0.f, 0.f, 0.f};
    for (int c = 0; c < HH / 16; c += 2) {
        int j0 = (c << 4) | l16, j1 = j0 + 16;
        const uint4* r0 = (const uint4*)(sWH + j0 * WHPITCH);
        const uint4* r1 = (const uint4*)(sWH + j1 * WHPITCH);
        uint4 w1a = r0[0], w2a = r0[1];
        uint4 w1b = r1[0], w2b = r1[1];
        float u0 = sb1[j0], u1 = sb1[j1];
        u0 = dot2u(w1a.x, zh[0], u0); u0 = dot2u(w1a.y, zh[1], u0);
        u0 = dot2u(w1a.z, zh[2], u0); u0 = dot2u(w1a.w, zh[3], u0);
        u1 = dot2u(w1b.x, zh[0], u1); u1 = dot2u(w1b.y, zh[1], u1);
        u1 = dot2u(w1b.z, zh[2], u1); u1 = dot2u(w1b.w, zh[3], u1);
        float ga0 = dot2u(w2a.x, gqh[0], 0.f);
        ga0 = dot2u(w2a.y, gqh[1], ga0);
        ga0 = dot2u(w2a.z, gqh[2], ga0);
        ga0 = dot2u(w2a.w, gqh[3], ga0);
        float ga1 = dot2u(w2b.x, gqh[0], 0.f);
        ga1 = dot2u(w2b.y, gqh[1], ga1);
        ga1 = dot2u(w2b.z, gqh[2], ga1);
        ga1 = dot2u(w2b.w, gqh[3], ga1);
        float g0 = (u0 > 0.f) ? av * ga0 : 0.f;
        float g1 = (u1 > 0.f) ? av * ga1 : 0.f;
        float2 f;
        f = u2f(w1a.x); gz[0] = fmaf(g0, f.x, gz[0]); gz[1] = fmaf(g0, f.y, gz[1]);
        f = u2f(w1a.y); gz[2] = fmaf(g0, f.x, gz[2]); gz[3] = fmaf(g0, f.y, gz[3]);
        f = u2f(w1a.z); gz[4] = fmaf(g0, f.x, gz[4]); gz[5] = fmaf(g0, f.y, gz[5]);
        f = u2f(w1a.w); gz[6] = fmaf(g0, f.x, gz[6]); gz[7] = fmaf(g0, f.y, gz[7]);
        f = u2f(w1b.x); gz[0] = fmaf(g1, f.x, gz[0]); gz[1] = fmaf(g1, f.y, gz[1]);
        f = u2f(w1b.y); gz[2] = fmaf(g1, f.x, gz[2]); gz[3] = fmaf(g1, f.y, gz[3]);
        f = u2f(w1b.z); gz[4] = fmaf(g1, f.x, gz[4]); gz[5] = fmaf(g1, f.y, gz[5]);
        f = u2f(w1b.w); gz[6] = fmaf(g1, f.x, gz[6]); gz[7] = fmaf(g1, f.y, gz[7]);
    }
#pragma unroll
    for (int m = 1; m < 16; m <<= 1)
#pragma unroll
        for (int k = 0; k < DD; k++) gz[k] += __shfl_xor(gz[k], m);
    float out_l = gz[0];
#pragma unroll
    for (int k = 1; k < DD; k++) out_l = (d == k) ? gz[k] : out_l;
    if (!sub) gz1b[(size_t)v * DD + d] = __float2half(bv * out_l);
}

// out[:, :D] = gh + a * AggOut(gz1b); 2 thr/node
__launch_bounds__(256)
__global__ void k_out_node(const int* __restrict__ start, const int* __restrict__ csr,
                           const __half* __restrict__ gz1b, const float* __restrict__ gh,
                           const float* __restrict__ a, float* __restrict__ out, int N) {
    int t = blockIdx.x * 256 + threadIdx.x;
    int v = t >> 1, half = t & 1;
    if (v >= N) return;
    int e0 = start[v], e1 = start[v + 1];
    int mid = e0 + ((e1 - e0) >> 1);
    float acc[8] = {0.f, 0.f, 0.f, 0.f, 0.f, 0.f, 0.f, 0.f};
    gather_h8(csr, gz1b, half ? mid : e0, half ? e1 : mid, acc);
#pragma unroll
    for (int k = 0; k < 8; k++) acc[k] += __shfl_xor(acc[k], 1);
    if (!half) {
        float av = a[v];
        const float4* gp = (const float4*)(gh + (size_t)v * DD);
        float4 g0 = gp[0], g1 = gp[1];
        float4* op = (float4*)(out + (size_t)v * 2 * DD);
        op[0] = make_float4(fmaf(av, acc[0], g0.x), fmaf(av, acc[1], g0.y),
                            fmaf(av, acc[2], g0.z), fmaf(av, acc[3], g0.w));
        op[1] = make_float4(fmaf(av, acc[4], g1.x), fmaf(av, acc[5], g1.y),
                            fmaf(av, acc[6], g1.z), fmaf(av, acc[7], g1.w));
    }
}

// ============================== launch =====================================

extern "C" void kernel_launch(void* const* d_in, const int* in_sizes, int n_in,
                              void* d_out, int out_size, void* d_ws, size_t ws_size,
                              hipStream_t stream) {
    const float* q    = (const float*)d_in[0];
    const float* p    = (const float*)d_in[1];
    const float* M    = (const float*)d_in[2];
    const int*   src  = (const int*)d_in[3];
    const int*   dst  = (const int*)d_in[4];
    const float* W1   = (const float*)d_in[5];
    const float* b1   = (const float*)d_in[6];
    const float* W2   = (const float*)d_in[7];
    const float* b2   = (const float*)d_in[8];
    const float* grav = (const float*)d_in[9];
    float* out = (float*)d_out;

    int N = in_sizes[0] / DD;
    int E = in_sizes[3];
    size_t n = (size_t)N;
    int NB = (N + 511) >> 9;

    // ---- data region (46N 4-byte words) ----
    float*   ws   = (float*)d_ws;
    float*   a_   = ws;             // N
    float*   b_   = ws + n;         // N
    __half*  qn   = (__half*)(ws + 2 * n);    // 8N half (4N words; region keeps 8N)
    float*   agg1 = ws + 10 * n;    // 8N f32 (live through bwd)
    float*   gh   = ws + 18 * n;    // 8N f32
    __half2* hm   = (__half2*)(ws + 26 * n);  // 8N half2 (8N words)
    __half*  ya   = (__half*)(ws + 34 * n);   // 8N half (4N words)
    __half*  bgh  = (__half*)(ws + 38 * n);   // 8N half (4N words)
    __half*  gz1b = (__half*)(ws + 42 * n);   // 8N half (4N words)

    // ---- int region ----
    int* iw        = (int*)(ws + 46 * n);
    int* csr_in    = iw;                       // E
    int* csr_out   = iw + (size_t)E;           // E
    int* start_in  = iw + 2 * (size_t)E;       // N+1
    int* start_out = start_in + n + 1;         // N+1
    int* gHistIn   = start_out + n + 1;        // 256
    int* gHistOut  = gHistIn + 256;            // 256
    int* cStartIn  = gHistOut + 256;           // NB+1
    int* cStartOut = cStartIn + NB + 1;        // NB+1
    int* cCurIn    = cStartOut + NB + 1;       // NB
    int* cCurOut   = cCurIn + NB;              // NB
    int* iwEnd     = cCurOut + NB;
    unsigned* W12h = (unsigned*)iwEnd;         // HH*WHPITCH = 3072 uints
    int* intAfter  = (int*)(W12h + HH * WHPITCH);
    // partition scratch: both dirs alias the data region (dead during build)
    int* P_in  = (E <= 16 * (long long)n) ? (int*)ws            : intAfter;
    int* P_out = (E <= 16 * (long long)n) ? (int*)(ws + 16 * n) : intAfter + E;

    hipMemsetAsync(gHistIn, 0, 512 * sizeof(int), stream);

    const int tb = 256;
    int gbN  = (N + tb - 1) / tb;
    int gb2  = (2 * N + tb - 1) / tb;          // 2 threads/node
    int gb4  = (4 * N + tb - 1) / tb;          // 4 threads/node
    int gb16 = (int)((16 * n + tb - 1) / tb);  // 16 lanes/node
    int gbC  = (E + CH - 1) / CH;

    // CSR build
    k_coarse  <<<gbC, tb, 0, stream>>>(src, dst, gHistIn, gHistOut, NB, E);
    k_cscan   <<<1, 256, 0, stream>>>(gHistIn, gHistOut, cStartIn, cStartOut,
                                      cCurIn, cCurOut, NB, E);
    k_part2   <<<dim3(gbC, 2), tb, 0, stream>>>(src, dst, cCurIn, cCurOut,
                                                P_in, P_out, NB, E);
    k_fine2   <<<dim3(NB, 2), 512, 0, stream>>>(cStartIn, cStartOut, P_in, P_out,
                                                start_in, start_out, csr_in, csr_out, N);
    k_prep    <<<gbN, tb, 0, stream>>>(q, p, M, W1, W2, W12h, start_in, start_out,
                                       a_, b_, hm, qn, out, N, E);

    // forward: [agg1 = AggIn(a*q)] + [ya = a*(relu((b*agg1)@W1+b1)@W2)] fused
    k_agg_mlp_fwd<<<gb16, tb, 0, stream>>>(start_in, csr_in, qn, a_, b_,
                                           W12h, b1, agg1, ya, N);
    // h = b * AggIn(ya) + b2 + q  -> .x halves of hm
    k_h_node  <<<gb2, tb, 0, stream>>>(start_in, csr_in, ya, b_, q, b2, hm, N);
    // gravity gradient (4 threads/node, full records in-thread)
    k_gh4     <<<gb4, tb, 0, stream>>>(start_in, csr_in, start_out, csr_out,
                                       hm, b_, grav, gh, bgh, N);
    // [gq = AggOut(bgh)] + [gz1b = b*((a*(gq@W2^T)*relu')@W1^T)] fused
    k_bgh_mlp_bwd<<<gb16, tb, 0, stream>>>(start_out, csr_out, bgh, agg1, a_, b_,
                                           W12h, b1, gz1b, N);
    // dHdQ = gh + a * AggOut(gz1b)
    k_out_node<<<gb2, tb, 0, stream>>>(start_out, csr_out, gz1b, gh, a_, out, N);
}

// Round 9
// 311.678 us; speedup vs baseline: 5.2682x; 1.0540x over previous
//
#include <hip/hip_runtime.h>
#include <hip/hip_fp16.h>

#define DD 8
#define HH 256
#define CH 8192          // edges per chunk in coarse/partition kernels
#define PAYBITS 17       // N <= 131072
#define PAYMASK 0x1FFFF
#define FPITCH 20        // fwd pair-pack pitch (uints): 80B, 16B-aligned, 2-way banks
#define BPITCH 28        // bwd pair-pack pitch (uints): 112B, 16B-aligned, 2-way banks

// R8 post-mortem: MLP kernels are NOT weight-LDS-bound. Remaining cost:
// (a) two serial 16-lane __shfl_xor reductions = dependent ds_bpermute chains
//     (~1200 stall-cycles/wave); (b) cvt+fma scatter sides of the c-loop.
// R9: (1) DPP-based reductions (VALU pipe, no LDS): quad_perm 0xB1/0x4E +
// row_half_mirror 0x141 + row_mirror 0x140; (2) pair-packed (j, j+16) fp16
// weights so every MAC is v_dot2_f32_f16 (f32 accumulate, no precision risk).

typedef _Float16 h2f __attribute__((ext_vector_type(2)));

static __device__ __forceinline__ float dot2u(unsigned w, h2f z, float c) {
#if __has_builtin(__builtin_amdgcn_fdot2)
    return __builtin_amdgcn_fdot2(__builtin_bit_cast(h2f, w), z, c, false);
#else
    __half2 h = __builtin_bit_cast(__half2, w);
    float2 f = __half22float2(h);
    return fmaf(f.y, (float)z[1], fmaf(f.x, (float)z[0], c));
#endif
}
static __device__ __forceinline__ h2f pkh(float a, float b) {
    h2f r; r[0] = (_Float16)a; r[1] = (_Float16)b; return r;
}
static __device__ __forceinline__ unsigned pk2(float a, float b) {
    __half2 hh; hh.x = __float2half(a); hh.y = __float2half(b);
    return *(unsigned*)&hh;
}

// ---- DPP lane-group sum (VALU pipe; no LDS round-trips) ----
template <int CTRL>
static __device__ __forceinline__ float dppadd(float x) {
    int y = __builtin_amdgcn_update_dpp(0, __builtin_bit_cast(int, x),
                                        CTRL, 0xF, 0xF, true);
    return x + __builtin_bit_cast(float, y);
}
// sum over 16-lane group (result in all 16 lanes)
static __device__ __forceinline__ void red16(float a[8]) {
#pragma unroll
    for (int k = 0; k < 8; k++) a[k] = dppadd<0xB1>(a[k]);   // xor1 (quad 1,0,3,2)
#pragma unroll
    for (int k = 0; k < 8; k++) a[k] = dppadd<0x4E>(a[k]);   // xor2 (quad 2,3,0,1)
#pragma unroll
    for (int k = 0; k < 8; k++) a[k] = dppadd<0x141>(a[k]);  // row_half_mirror
#pragma unroll
    for (int k = 0; k < 8; k++) a[k] = dppadd<0x140>(a[k]);  // row_mirror
}
static __device__ __forceinline__ void red2(float a[8]) {
#pragma unroll
    for (int k = 0; k < 8; k++) a[k] = dppadd<0xB1>(a[k]);
}
static __device__ __forceinline__ void red4(float a[8]) {
#pragma unroll
    for (int k = 0; k < 8; k++) a[k] = dppadd<0xB1>(a[k]);
#pragma unroll
    for (int k = 0; k < 8; k++) a[k] = dppadd<0x4E>(a[k]);
}

// ============================ CSR construction ==============================

__global__ void k_coarse(const int* __restrict__ src, const int* __restrict__ dst,
                         int* __restrict__ gHistIn, int* __restrict__ gHistOut,
                         int NB, int E) {
    __shared__ int hIn[256], hOut[256];
    if (threadIdx.x < 256) { hIn[threadIdx.x] = 0; hOut[threadIdx.x] = 0; }
    __syncthreads();
    int lo = blockIdx.x * CH;
    int hi = min(lo + CH, E);
    for (int i = lo + threadIdx.x; i < hi; i += blockDim.x) {
        atomicAdd(&hIn[dst[i] >> 9], 1);
        atomicAdd(&hOut[src[i] >> 9], 1);
    }
    __syncthreads();
    if (threadIdx.x < NB) {
        int ci = hIn[threadIdx.x], co = hOut[threadIdx.x];
        if (ci) atomicAdd(&gHistIn[threadIdx.x], ci);
        if (co) atomicAdd(&gHistOut[threadIdx.x], co);
    }
}

__global__ void k_cscan(const int* __restrict__ gHistIn, const int* __restrict__ gHistOut,
                        int* __restrict__ cStartIn, int* __restrict__ cStartOut,
                        int* __restrict__ cCurIn, int* __restrict__ cCurOut,
                        int NB, int E) {
    __shared__ int s[256];
#pragma unroll
    for (int dir = 0; dir < 2; dir++) {
        const int* gh = dir ? gHistOut : gHistIn;
        int* cs = dir ? cStartOut : cStartIn;
        int* cc = dir ? cCurOut : cCurIn;
        int v = (threadIdx.x < NB) ? gh[threadIdx.x] : 0;
        s[threadIdx.x] = v;
        __syncthreads();
        for (int off = 1; off < 256; off <<= 1) {
            int t = (threadIdx.x >= off) ? s[threadIdx.x - off] : 0;
            __syncthreads();
            s[threadIdx.x] += t;
            __syncthreads();
        }
        if (threadIdx.x < NB) {
            int ex = s[threadIdx.x] - v;
            cs[threadIdx.x] = ex;
            cc[threadIdx.x] = ex;
        }
        if (threadIdx.x == 0) cs[NB] = E;
        __syncthreads();
    }
}

__global__ void k_part2(const int* __restrict__ src, const int* __restrict__ dst,
                        int* __restrict__ cCurIn, int* __restrict__ cCurOut,
                        int* __restrict__ P_in, int* __restrict__ P_out,
                        int NB, int E) {
    int dir = blockIdx.y;
    const int* key = dir ? src : dst;
    const int* pay = dir ? dst : src;
    int* cCur = dir ? cCurOut : cCurIn;
    int* P    = dir ? P_out   : P_in;
    __shared__ int h[256];
    if (threadIdx.x < 256) h[threadIdx.x] = 0;
    __syncthreads();
    int lo = blockIdx.x * CH;
    int hi = min(lo + CH, E);
    for (int i = lo + threadIdx.x; i < hi; i += blockDim.x)
        atomicAdd(&h[key[i] >> 9], 1);
    __syncthreads();
    if (threadIdx.x < NB) {
        int c = h[threadIdx.x];
        h[threadIdx.x] = c ? atomicAdd(&cCur[threadIdx.x], c) : 0;
    }
    __syncthreads();
    for (int i = lo + threadIdx.x; i < hi; i += blockDim.x) {
        int k = key[i];
        int pos = atomicAdd(&h[k >> 9], 1);
        P[pos] = ((k & 511) << PAYBITS) | pay[i];
    }
}

__launch_bounds__(512)
__global__ void k_fine2(const int* __restrict__ cStartIn, const int* __restrict__ cStartOut,
                        const int* __restrict__ P_in, const int* __restrict__ P_out,
                        int* __restrict__ start_in, int* __restrict__ start_out,
                        int* __restrict__ csr_in, int* __restrict__ csr_out, int N) {
    int dir = blockIdx.y;
    const int* cStart = dir ? cStartOut : cStartIn;
    const int* P      = dir ? P_out     : P_in;
    int* start        = dir ? start_out : start_in;
    int* csr          = dir ? csr_out   : csr_in;
    __shared__ int cnt[512], scn[512];
    int b = blockIdx.x;
    int lo = cStart[b], hi = cStart[b + 1];
    cnt[threadIdx.x] = 0;
    __syncthreads();
    for (int i = lo + threadIdx.x; i < hi; i += 512)
        atomicAdd(&cnt[P[i] >> PAYBITS], 1);
    __syncthreads();
    int own = cnt[threadIdx.x];
    scn[threadIdx.x] = own;
    __syncthreads();
    for (int off = 1; off < 512; off <<= 1) {
        int t = (threadIdx.x >= off) ? scn[threadIdx.x - off] : 0;
        __syncthreads();
        scn[threadIdx.x] += t;
        __syncthreads();
    }
    int base = lo + scn[threadIdx.x] - own;
    int node = (b << 9) + threadIdx.x;
    if (node < N) start[node] = base;
    cnt[threadIdx.x] = base;   // reuse as cursor
    __syncthreads();
    for (int i = lo + threadIdx.x; i < hi; i += 512) {
        int p = P[i];
        int pos = atomicAdd(&cnt[p >> PAYBITS], 1);
        csr[pos] = p & PAYMASK;
    }
}

// ==== per-node prep (norms, masses, dHdP) + pair-packed fp16 weights =======
// pair pid: ci=pid>>4, l16=pid&15 -> rows (j0 = ci*32+l16, j1 = j0+16)
// Fwd pack [20]: 0..3 W1col j0 (d-pairs) | 4..7 W1col j1 | 8..15 k:(W2[j0][k],W2[j1][k])
// Bwd pack [28]: 0..7 as fwd | 8..11 kk:(W2[j0][2kk],W2[j0][2kk+1]) | 12..15 j1 same
//                | 16..23 d:(W1[d][j0],W1[d][j1]) | 24..27 pad
__global__ void k_prep(const float* __restrict__ q, const float* __restrict__ p,
                       const float* __restrict__ M,
                       const float* __restrict__ W1, const float* __restrict__ W2,
                       unsigned* __restrict__ Fp, unsigned* __restrict__ Bp,
                       int* __restrict__ start_in, int* __restrict__ start_out,
                       float* __restrict__ a, float* __restrict__ b,
                       __half2* __restrict__ hm, __half* __restrict__ qn,
                       float* __restrict__ out, int N, int E) {
    int t = blockIdx.x * blockDim.x + threadIdx.x;
    if (t == 0) { start_in[N] = E; start_out[N] = E; }
    if (t < 128) {                       // one thread packs one (j0, j0+16) pair
        int ci = t >> 4, l16 = t & 15;
        int j0 = ci * 32 + l16, j1 = j0 + 16;
        unsigned* F = Fp + t * FPITCH;
        unsigned* B = Bp + t * BPITCH;
#pragma unroll
        for (int k = 0; k < 4; k++) {
            unsigned c0 = pk2(W1[(2 * k) * HH + j0], W1[(2 * k + 1) * HH + j0]);
            unsigned c1 = pk2(W1[(2 * k) * HH + j1], W1[(2 * k + 1) * HH + j1]);
            F[k] = c0; F[4 + k] = c1; B[k] = c0; B[4 + k] = c1;
        }
#pragma unroll
        for (int k = 0; k < 8; k++)
            F[8 + k] = pk2(W2[j0 * DD + k], W2[j1 * DD + k]);
#pragma unroll
        for (int kk = 0; kk < 4; kk++) {
            B[8 + kk]  = pk2(W2[j0 * DD + 2 * kk], W2[j0 * DD + 2 * kk + 1]);
            B[12 + kk] = pk2(W2[j1 * DD + 2 * kk], W2[j1 * DD + 2 * kk + 1]);
        }
#pragma unroll
        for (int d = 0; d < 8; d++)
            B[16 + d] = pk2(W1[d * HH + j0], W1[d * HH + j1]);
        B[24] = 0; B[25] = 0; B[26] = 0; B[27] = 0;
    }
    int v = t;
    if (v >= N) return;
    int ei1 = (v + 1 < N) ? start_in[v + 1]  : E;
    int eo1 = (v + 1 < N) ? start_out[v + 1] : E;
    float din  = (float)(ei1 - start_in[v]);
    float dout = (float)(eo1 - start_out[v]);
    float av = 1.0f / sqrtf(dout > 0.f ? dout : 1.f);   // norm_src
    float bv = 1.0f / sqrtf(din  > 0.f ? din  : 1.f);   // norm_dst
    a[v] = av; b[v] = bv;
#pragma unroll
    for (int d = 0; d < DD; d++) {
        float m = M[(size_t)v * DD * DD + d * (DD + 1)];
        __half2 hmv;
        hmv.x = __float2half(0.f);
        hmv.y = __float2half(m);
        hm[(size_t)v * DD + d] = hmv;
        qn[(size_t)v * DD + d] = __float2half(av * q[(size_t)v * DD + d]);
        out[(size_t)v * 2 * DD + DD + d] = p[(size_t)v * DD + d] / m;  // dHdP
    }
}

// ------------------- record unpack/accumulate helpers -----------------------
static __device__ __forceinline__
void acc_h8(uint4 r, float acc[8]) {
    float2 f;
    f = __half22float2(*(__half2*)&r.x); acc[0] += f.x; acc[1] += f.y;
    f = __half22float2(*(__half2*)&r.y); acc[2] += f.x; acc[3] += f.y;
    f = __half22float2(*(__half2*)&r.z); acc[4] += f.x; acc[5] += f.y;
    f = __half22float2(*(__half2*)&r.w); acc[6] += f.x; acc[7] += f.y;
}

static __device__ __forceinline__
void unpack_hm(uint4 r0, uint4 r1, float h[8], float m[8]) {
    float2 f;
    f = __half22float2(*(__half2*)&r0.x); h[0] = f.x; m[0] = f.y;
    f = __half22float2(*(__half2*)&r0.y); h[1] = f.x; m[1] = f.y;
    f = __half22float2(*(__half2*)&r0.z); h[2] = f.x; m[2] = f.y;
    f = __half22float2(*(__half2*)&r0.w); h[3] = f.x; m[3] = f.y;
    f = __half22float2(*(__half2*)&r1.x); h[4] = f.x; m[4] = f.y;
    f = __half22float2(*(__half2*)&r1.y); h[5] = f.x; m[5] = f.y;
    f = __half22float2(*(__half2*)&r1.z); h[6] = f.x; m[6] = f.y;
    f = __half22float2(*(__half2*)&r1.w); h[7] = f.x; m[7] = f.y;
}

// gather full half8 records over csr range into acc[8]
static __device__ __forceinline__
void gather_h8(const int* __restrict__ csr, const __half* __restrict__ x,
               int e, int e1, float acc[8]) {
    for (; e + 3 < e1; e += 4) {
        int u0 = csr[e], u1 = csr[e + 1], u2 = csr[e + 2], u3 = csr[e + 3];
        uint4 r0 = *(const uint4*)(x + (size_t)u0 * DD);
        uint4 r1 = *(const uint4*)(x + (size_t)u1 * DD);
        uint4 r2 = *(const uint4*)(x + (size_t)u2 * DD);
        uint4 r3 = *(const uint4*)(x + (size_t)u3 * DD);
        acc_h8(r0, acc); acc_h8(r1, acc); acc_h8(r2, acc); acc_h8(r3, acc);
    }
    for (; e < e1; e++) {
        uint4 r = *(const uint4*)(x + (size_t)csr[e] * DD);
        acc_h8(r, acc);
    }
}

// ===== FUSED: agg1 = AggIn(qn) + MLP forward, 16 lanes/node, pair-dot2 =====
__launch_bounds__(256)
__global__ void k_agg_mlp_fwd(const int* __restrict__ start, const int* __restrict__ csr,
                              const __half* __restrict__ qn,
                              const float* __restrict__ a, const float* __restrict__ b,
                              const unsigned* __restrict__ Fp, const float* __restrict__ b1,
                              float* __restrict__ agg1, __half* __restrict__ ya, int N) {
    __shared__ unsigned sF[128 * FPITCH];   // 10 KB
    __shared__ float sb1[HH];
    for (int i = threadIdx.x; i < 128 * FPITCH; i += 256) sF[i] = Fp[i];
    for (int i = threadIdx.x; i < HH; i += 256) sb1[i] = b1[i];
    __syncthreads();
    int t = blockIdx.x * 256 + threadIdx.x;
    int v = t >> 4, l16 = t & 15, sub = (t >> 3) & 1, d = t & 7;
    if (v >= N) return;
    int e0 = start[v], e1 = start[v + 1];
    // gather fp16 qn records: 16-way split of the in-edge range
    float ag[DD] = {0.f, 0.f, 0.f, 0.f, 0.f, 0.f, 0.f, 0.f};
    for (int e = e0 + l16; e < e1; e += 16) {
        uint4 r = *(const uint4*)(qn + (size_t)csr[e] * DD);
        acc_h8(r, ag);
    }
    red16(ag);                               // DPP: no LDS round-trips
    // persist agg1 f32 (needed by bwd recompute of z)
    if (l16 < 2) {
        float4 val = l16 ? make_float4(ag[4], ag[5], ag[6], ag[7])
                         : make_float4(ag[0], ag[1], ag[2], ag[3]);
        ((float4*)(agg1 + (size_t)v * DD))[l16] = val;
    }
    float bv = b[v];
    h2f zh[4];
#pragma unroll
    for (int k = 0; k < 4; k++) zh[k] = pkh(bv * ag[2 * k], bv * ag[2 * k + 1]);
    float acc[DD] = {0.f, 0.f, 0.f, 0.f, 0.f, 0.f, 0.f, 0.f};
#pragma unroll
    for (int ci = 0; ci < 8; ci++) {
        int pid = ci * 16 + l16;
        const uint4* pw = (const uint4*)(sF + pid * FPITCH);
        uint4 w1a = pw[0], w1b = pw[1], w2p0 = pw[2], w2p1 = pw[3];
        int j0 = ci * 32 + l16;
        float u0 = sb1[j0], u1 = sb1[j0 + 16];
        u0 = dot2u(w1a.x, zh[0], u0); u0 = dot2u(w1a.y, zh[1], u0);
        u0 = dot2u(w1a.z, zh[2], u0); u0 = dot2u(w1a.w, zh[3], u0);
        u1 = dot2u(w1b.x, zh[0], u1); u1 = dot2u(w1b.y, zh[1], u1);
        u1 = dot2u(w1b.z, zh[2], u1); u1 = dot2u(w1b.w, zh[3], u1);
        h2f hh = pkh(fmaxf(u0, 0.f), fmaxf(u1, 0.f));
        acc[0] = dot2u(w2p0.x, hh, acc[0]); acc[1] = dot2u(w2p0.y, hh, acc[1]);
        acc[2] = dot2u(w2p0.z, hh, acc[2]); acc[3] = dot2u(w2p0.w, hh, acc[3]);
        acc[4] = dot2u(w2p1.x, hh, acc[4]); acc[5] = dot2u(w2p1.y, hh, acc[5]);
        acc[6] = dot2u(w2p1.z, hh, acc[6]); acc[7] = dot2u(w2p1.w, hh, acc[7]);
    }
    red16(acc);
    float yl = acc[0];
#pragma unroll
    for (int k = 1; k < DD; k++) yl = (d == k) ? acc[k] : yl;
    if (!sub) ya[(size_t)v * DD + d] = __float2half(a[v] * yl);
}

// h = b*AggIn(ya) + b2 + q  -> .x halves of hm records; 2 thr/node
__launch_bounds__(256)
__global__ void k_h_node(const int* __restrict__ start, const int* __restrict__ csr,
                         const __half* __restrict__ ya, const float* __restrict__ b,
                         const float* __restrict__ q, const float* __restrict__ b2,
                         __half2* __restrict__ hm, int N) {
    int t = blockIdx.x * 256 + threadIdx.x;
    int v = t >> 1, half = t & 1;
    if (v >= N) return;
    int e0 = start[v], e1 = start[v + 1];
    int mid = e0 + ((e1 - e0) >> 1);
    float acc[8] = {0.f, 0.f, 0.f, 0.f, 0.f, 0.f, 0.f, 0.f};
    gather_h8(csr, ya, half ? mid : e0, half ? e1 : mid, acc);
    red2(acc);
    if (!half) {
        float bv = b[v];
        const float4* qp = (const float4*)(q + (size_t)v * DD);
        float4 q0 = qp[0], q1 = qp[1];
        float hq[8] = {q0.x, q0.y, q0.z, q0.w, q1.x, q1.y, q1.z, q1.w};
        __half2* hp = hm + (size_t)v * DD;
#pragma unroll
        for (int k = 0; k < DD; k++) {
            float hval = fmaf(bv, acc[k], b2[k] + hq[k]);
            __half2 cur = hp[k];
            cur.x = __float2half(hval);
            hp[k] = cur;
        }
    }
}

// gravity gradient: 4 threads/node (dir x half-range), full records in-thread
__launch_bounds__(256)
__global__ void k_gh4(const int* __restrict__ start_in, const int* __restrict__ csr_in,
                      const int* __restrict__ start_out, const int* __restrict__ csr_out,
                      const __half2* __restrict__ hm,
                      const float* __restrict__ b, const float* __restrict__ grav,
                      float* __restrict__ gh, __half* __restrict__ bgh, int N) {
    int t = blockIdx.x * 256 + threadIdx.x;
    int v = t >> 2, sub = t & 3, dir = sub >> 1, half = sub & 1;
    if (v >= N) return;
    const uint4* srec = (const uint4*)(hm + (size_t)v * DD);
    uint4 s0 = srec[0], s1 = srec[1];
    float hv[8], mv[8];
    unpack_hm(s0, s1, hv, mv);
    const int* start = dir ? start_out : start_in;
    const int* csr   = dir ? csr_out   : csr_in;
    int e0 = start[v], e1 = start[v + 1];
    int mid = e0 + ((e1 - e0) >> 1);
    int e = half ? mid : e0, hi = half ? e1 : mid;
    float coef = -0.5f * grav[0];
    float acc[8] = {0.f, 0.f, 0.f, 0.f, 0.f, 0.f, 0.f, 0.f};
    for (; e + 1 < hi; e += 2) {
        int u0 = csr[e], u1 = csr[e + 1];
        const uint4* r0p = (const uint4*)(hm + (size_t)u0 * DD);
        const uint4* r1p = (const uint4*)(hm + (size_t)u1 * DD);
        uint4 x0 = r0p[0], x1 = r0p[1], y0 = r1p[0], y1 = r1p[1];
        float hu0[8], mu0[8], hu1[8], mu1[8];
        unpack_hm(x0, x1, hu0, mu0);
        unpack_hm(y0, y1, hu1, mu1);
        float d0[8], d1[8];
        float e20 = 0.f, S0 = 0.f, e21 = 0.f, S1 = 0.f;
#pragma unroll
        for (int k = 0; k < 8; k++) {
            d0[k] = hv[k] - hu0[k];
            d1[k] = hv[k] - hu1[k];
            e20 = fmaf(d0[k], d0[k], e20);
            e21 = fmaf(d1[k], d1[k], e21);
            S0 = fmaf(mv[k], mu0[k], S0);
            S1 = fmaf(mv[k], mu1[k], S1);
        }
        float r0 = rsqrtf(e20), r1 = rsqrtf(e21);
        float c0 = coef * S0 * r0 * r0 * r0;
        float c1 = coef * S1 * r1 * r1 * r1;
#pragma unroll
        for (int k = 0; k < 8; k++)
            acc[k] = fmaf(c0, d0[k], fmaf(c1, d1[k], acc[k]));
    }
    if (e < hi) {
        int u = csr[e];
        const uint4* rp = (const uint4*)(hm + (size_t)u * DD);
        uint4 x0 = rp[0], x1 = rp[1];
        float hu[8], mu[8];
        unpack_hm(x0, x1, hu, mu);
        float df[8];
        float e2 = 0.f, S = 0.f;
#pragma unroll
        for (int k = 0; k < 8; k++) {
            df[k] = hv[k] - hu[k];
            e2 = fmaf(df[k], df[k], e2);
            S = fmaf(mv[k], mu[k], S);
        }
        float r = rsqrtf(e2);
        float c = coef * S * r * r * r;
#pragma unroll
        for (int k = 0; k < 8; k++) acc[k] = fmaf(c, df[k], acc[k]);
    }
    red4(acc);   // combine the 4 subset threads (adjacent lanes) via DPP
    if (sub == 0) {
        float4* gp = (float4*)(gh + (size_t)v * DD);
        gp[0] = make_float4(acc[0], acc[1], acc[2], acc[3]);
        gp[1] = make_float4(acc[4], acc[5], acc[6], acc[7]);
        float bv = b[v];
        __half2* bp = (__half2*)(bgh + (size_t)v * DD);
        bp[0] = __floats2half2_rn(bv * acc[0], bv * acc[1]);
        bp[1] = __floats2half2_rn(bv * acc[2], bv * acc[3]);
        bp[2] = __floats2half2_rn(bv * acc[4], bv * acc[5]);
        bp[3] = __floats2half2_rn(bv * acc[6], bv * acc[7]);
    }
}

// ===== FUSED: gq = AggOut(bgh) + MLP backward, 16 lanes/node, pair-dot2 =====
__launch_bounds__(256)
__global__ void k_bgh_mlp_bwd(const int* __restrict__ start, const int* __restrict__ csr,
                              const __half* __restrict__ bgh,
                              const float* __restrict__ agg1,
                              const float* __restrict__ a, const float* __restrict__ b,
                              const unsigned* __restrict__ Bp, const float* __restrict__ b1,
                              __half* __restrict__ gz1b, int N) {
    __shared__ unsigned sB[128 * BPITCH];   // 14 KB
    __shared__ float sb1[HH];
    for (int i = threadIdx.x; i < 128 * BPITCH; i += 256) sB[i] = Bp[i];
    for (int i = threadIdx.x; i < HH; i += 256) sb1[i] = b1[i];
    __syncthreads();
    int t = blockIdx.x * 256 + threadIdx.x;
    int v = t >> 4, l16 = t & 15, sub = (t >> 3) & 1, d = t & 7;
    if (v >= N) return;
    int e0 = start[v], e1 = start[v + 1];
    // gather AggOut(bgh): 16-way split of the out-edge range
    float gq[DD] = {0.f, 0.f, 0.f, 0.f, 0.f, 0.f, 0.f, 0.f};
    for (int e = e0 + l16; e < e1; e += 16) {
        uint4 r = *(const uint4*)(bgh + (size_t)csr[e] * DD);
        acc_h8(r, gq);
    }
    red16(gq);                               // DPP reduction
    float bv = b[v], av = a[v];
    // z from agg1 directly (wave-uniform per node -> broadcast load, no shfl)
    const float4* ap = (const float4*)(agg1 + (size_t)v * DD);
    float4 a0 = ap[0], a1 = ap[1];
    h2f zh[4], gqh[4];
    zh[0] = pkh(bv * a0.x, bv * a0.y); zh[1] = pkh(bv * a0.z, bv * a0.w);
    zh[2] = pkh(bv * a1.x, bv * a1.y); zh[3] = pkh(bv * a1.z, bv * a1.w);
#pragma unroll
    for (int k = 0; k < 4; k++) gqh[k] = pkh(gq[2 * k], gq[2 * k + 1]);
    float gz[DD] = {0.f, 0.f, 0.f, 0.f, 0.f, 0.f, 0.f, 0.f};
#pragma unroll
    for (int ci = 0; ci < 8; ci++) {
        int pid = ci * 16 + l16;
        const uint4* pw = (const uint4*)(sB + pid * BPITCH);
        uint4 w1a = pw[0], w1b = pw[1], w2r0 = pw[2], w2r1 = pw[3];
        uint4 g0p = pw[4], g1p = pw[5];
        int j0 = ci * 32 + l16;
        float u0 = sb1[j0], u1 = sb1[j0 + 16];
        u0 = dot2u(w1a.x, zh[0], u0); u0 = dot2u(w1a.y, zh[1], u0);
        u0 = dot2u(w1a.z, zh[2], u0); u0 = dot2u(w1a.w, zh[3], u0);
        u1 = dot2u(w1b.x, zh[0], u1); u1 = dot2u(w1b.y, zh[1], u1);
        u1 = dot2u(w1b.z, zh[2], u1); u1 = dot2u(w1b.w, zh[3], u1);
        float ga0 = dot2u(w2r0.x, gqh[0], 0.f);
        ga0 = dot2u(w2r0.y, gqh[1], ga0);
        ga0 = dot2u(w2r0.z, gqh[2], ga0);
        ga0 = dot2u(w2r0.w, gqh[3], ga0);
        float ga1 = dot2u(w2r1.x, gqh[0], 0.f);
        ga1 = dot2u(w2r1.y, gqh[1], ga1);
        ga1 = dot2u(w2r1.z, gqh[2], ga1);
        ga1 = dot2u(w2r1.w, gqh[3], ga1);
        float g0 = (u0 > 0.f) ? av * ga0 : 0.f;
        float g1 = (u1 > 0.f) ? av * ga1 : 0.f;
        h2f gg = pkh(g0, g1);
        gz[0] = dot2u(g0p.x, gg, gz[0]); gz[1] = dot2u(g0p.y, gg, gz[1]);
        gz[2] = dot2u(g0p.z, gg, gz[2]); gz[3] = dot2u(g0p.w, gg, gz[3]);
        gz[4] = dot2u(g1p.x, gg, gz[4]); gz[5] = dot2u(g1p.y, gg, gz[5]);
        gz[6] = dot2u(g1p.z, gg, gz[6]); gz[7] = dot2u(g1p.w, gg, gz[7]);
    }
    red16(gz);
    float out_l = gz[0];
#pragma unroll
    for (int k = 1; k < DD; k++) out_l = (d == k) ? gz[k] : out_l;
    if (!sub) gz1b[(size_t)v * DD + d] = __float2half(bv * out_l);
}

// out[:, :D] = gh + a * AggOut(gz1b); 2 thr/node
__launch_bounds__(256)
__global__ void k_out_node(const int* __restrict__ start, const int* __restrict__ csr,
                           const __half* __restrict__ gz1b, const float* __restrict__ gh,
                           const float* __restrict__ a, float* __restrict__ out, int N) {
    int t = blockIdx.x * 256 + threadIdx.x;
    int v = t >> 1, half = t & 1;
    if (v >= N) return;
    int e0 = start[v], e1 = start[v + 1];
    int mid = e0 + ((e1 - e0) >> 1);
    float acc[8] = {0.f, 0.f, 0.f, 0.f, 0.f, 0.f, 0.f, 0.f};
    gather_h8(csr, gz1b, half ? mid : e0, half ? e1 : mid, acc);
    red2(acc);
    if (!half) {
        float av = a[v];
        const float4* gp = (const float4*)(gh + (size_t)v * DD);
        float4 g0 = gp[0], g1 = gp[1];
        float4* op = (float4*)(out + (size_t)v * 2 * DD);
        op[0] = make_float4(fmaf(av, acc[0], g0.x), fmaf(av, acc[1], g0.y),
                            fmaf(av, acc[2], g0.z), fmaf(av, acc[3], g0.w));
        op[1] = make_float4(fmaf(av, acc[4], g1.x), fmaf(av, acc[5], g1.y),
                            fmaf(av, acc[6], g1.z), fmaf(av, acc[7], g1.w));
    }
}

// ============================== launch =====================================

extern "C" void kernel_launch(void* const* d_in, const int* in_sizes, int n_in,
                              void* d_out, int out_size, void* d_ws, size_t ws_size,
                              hipStream_t stream) {
    const float* q    = (const float*)d_in[0];
    const float* p    = (const float*)d_in[1];
    const float* M    = (const float*)d_in[2];
    const int*   src  = (const int*)d_in[3];
    const int*   dst  = (const int*)d_in[4];
    const float* W1   = (const float*)d_in[5];
    const float* b1   = (const float*)d_in[6];
    const float* W2   = (const float*)d_in[7];
    const float* b2   = (const float*)d_in[8];
    const float* grav = (const float*)d_in[9];
    float* out = (float*)d_out;

    int N = in_sizes[0] / DD;
    int E = in_sizes[3];
    size_t n = (size_t)N;
    int NB = (N + 511) >> 9;

    // ---- data region (46N 4-byte words) ----
    float*   ws   = (float*)d_ws;
    float*   a_   = ws;             // N
    float*   b_   = ws + n;         // N
    __half*  qn   = (__half*)(ws + 2 * n);    // 8N half (4N words; region keeps 8N)
    float*   agg1 = ws + 10 * n;    // 8N f32 (live through bwd)
    float*   gh   = ws + 18 * n;    // 8N f32
    __half2* hm   = (__half2*)(ws + 26 * n);  // 8N half2 (8N words)
    __half*  ya   = (__half*)(ws + 34 * n);   // 8N half (4N words)
    __half*  bgh  = (__half*)(ws + 38 * n);   // 8N half (4N words)
    __half*  gz1b = (__half*)(ws + 42 * n);   // 8N half (4N words)

    // ---- int region ----
    int* iw        = (int*)(ws + 46 * n);
    int* csr_in    = iw;                       // E
    int* csr_out   = iw + (size_t)E;           // E
    int* start_in  = iw + 2 * (size_t)E;       // N+1
    int* start_out = start_in + n + 1;         // N+1
    int* gHistIn   = start_out + n + 1;        // 256
    int* gHistOut  = gHistIn + 256;            // 256
    int* cStartIn  = gHistOut + 256;           // NB+1
    int* cStartOut = cStartIn + NB + 1;        // NB+1
    int* cCurIn    = cStartOut + NB + 1;       // NB
    int* cCurOut   = cCurIn + NB;              // NB
    int* iwEnd     = cCurOut + NB;
    unsigned* Fp   = (unsigned*)iwEnd;         // 128*FPITCH = 2560 uints
    unsigned* Bp   = Fp + 128 * FPITCH;        // 128*BPITCH = 3584 uints
    int* intAfter  = (int*)(Bp + 128 * BPITCH);
    // partition scratch: both dirs alias the data region (dead during build)
    int* P_in  = (E <= 16 * (long long)n) ? (int*)ws            : intAfter;
    int* P_out = (E <= 16 * (long long)n) ? (int*)(ws + 16 * n) : intAfter + E;

    hipMemsetAsync(gHistIn, 0, 512 * sizeof(int), stream);

    const int tb = 256;
    int gbN  = (N + tb - 1) / tb;
    int gb2  = (2 * N + tb - 1) / tb;          // 2 threads/node
    int gb4  = (4 * N + tb - 1) / tb;          // 4 threads/node
    int gb16 = (int)((16 * n + tb - 1) / tb);  // 16 lanes/node
    int gbC  = (E + CH - 1) / CH;

    // CSR build
    k_coarse  <<<gbC, tb, 0, stream>>>(src, dst, gHistIn, gHistOut, NB, E);
    k_cscan   <<<1, 256, 0, stream>>>(gHistIn, gHistOut, cStartIn, cStartOut,
                                      cCurIn, cCurOut, NB, E);
    k_part2   <<<dim3(gbC, 2), tb, 0, stream>>>(src, dst, cCurIn, cCurOut,
                                                P_in, P_out, NB, E);
    k_fine2   <<<dim3(NB, 2), 512, 0, stream>>>(cStartIn, cStartOut, P_in, P_out,
                                                start_in, start_out, csr_in, csr_out, N);
    k_prep    <<<gbN, tb, 0, stream>>>(q, p, M, W1, W2, Fp, Bp, start_in, start_out,
                                       a_, b_, hm, qn, out, N, E);

    // forward: [agg1 = AggIn(a*q)] + [ya = a*(relu((b*agg1)@W1+b1)@W2)] fused
    k_agg_mlp_fwd<<<gb16, tb, 0, stream>>>(start_in, csr_in, qn, a_, b_,
                                           Fp, b1, agg1, ya, N);
    // h = b * AggIn(ya) + b2 + q  -> .x halves of hm
    k_h_node  <<<gb2, tb, 0, stream>>>(start_in, csr_in, ya, b_, q, b2, hm, N);
    // gravity gradient (4 threads/node, full records in-thread)
    k_gh4     <<<gb4, tb, 0, stream>>>(start_in, csr_in, start_out, csr_out,
                                       hm, b_, grav, gh, bgh, N);
    // [gq = AggOut(bgh)] + [gz1b = b*((a*(gq@W2^T)*relu')@W1^T)] fused
    k_bgh_mlp_bwd<<<gb16, tb, 0, stream>>>(start_out, csr_out, bgh, agg1, a_, b_,
                                           Bp, b1, gz1b, N);
    // dHdQ = gh + a * AggOut(gz1b)
    k_out_node<<<gb2, tb, 0, stream>>>(start_out, csr_out, gz1b, gh, a_, out, N);
}